// Round 2
// baseline (1815.161 us; speedup 1.0000x reference)
//
#include <hip/hip_runtime.h>

// MambaEncoder: B=2, L=2048, D_MODEL=512, D_INNER=1024, DT_RANK=32, D_STATE=16, 4 blocks.
// Round 2: dtype-agnostic. A probe kernel detects whether inputs are bf16 or fp32 (writes a
// flag to ws); all input loads branch on the flag (wave-uniform). Compute is fp32 throughout.
// GEMMs: LDS-tiled 64x64x16, 4x4/thread. Scan: 3-phase chunked (32 chunks x 64 steps) using
// dA = exp(A[s]*dt) => chunk decay summary is exp(A[s]*sum(dt)) -> one scalar per (b,c,d).

#define L_    2048
#define DM    512
#define DI    1024
#define DS    16
#define NBLK  4
#define NC    32
#define CH    64
#define MROWS 4096   // B_ * L_

using u16 = unsigned short;

__device__ __forceinline__ float b2f(u16 u) {
    union { unsigned int i; float f; } v; v.i = ((unsigned int)u) << 16; return v.f;
}
__device__ __forceinline__ u16 f2b(float f) {
    union { float f; unsigned int i; } v; v.f = f;
    unsigned int x = v.i;
    return (u16)((x + 0x7FFFu + ((x >> 16) & 1u)) >> 16);
}
__device__ __forceinline__ float silu_(float x) { return x / (1.f + expf(-x)); }

struct F4 { float x, y, z, w; };
// e must be a multiple of 4 for alignment. Loads 4 consecutive elements of an input tensor.
__device__ __forceinline__ F4 load4(const void* p, size_t e, bool isbf) {
    F4 r;
    if (isbf) {
        ushort4 v = *(const ushort4*)((const u16*)p + e);
        r.x = b2f(v.x); r.y = b2f(v.y); r.z = b2f(v.z); r.w = b2f(v.w);
    } else {
        float4 v = *(const float4*)((const float*)p + e);
        r.x = v.x; r.y = v.y; r.z = v.z; r.w = v.w;
    }
    return r;
}
__device__ __forceinline__ float load1(const void* p, size_t e, bool isbf) {
    return isbf ? b2f(((const u16*)p)[e]) : ((const float*)p)[e];
}

// ---------------- dtype probe: bf16 iff first 64Ki u16s are all plausible bf16 ----------------
__global__ void probe_dtype(const void* x, float* flag) {
    __shared__ int allok;
    if (threadIdx.x == 0) allok = 1;
    __syncthreads();
    const u16* p = (const u16*)x;
    bool ok = true;
    for (int i = threadIdx.x; i < 65536; i += 256) {
        float v = b2f(p[i]);
        if (!(v == v) || fabsf(v) >= 1000.f) ok = false;
    }
    if (!ok) allok = 0;
    __syncthreads();
    if (threadIdx.x == 0) flag[0] = allok ? 1.f : 0.f;
}

// ---------------- GEMM: C(fp32) = A(fp32) @ B(input dtype)  [+ epilogue] ----------------
// EP 0: none; EP 1: softplus(acc + bias[col]); EP 2: acc + resid[row*ldc+col]
template<int EP>
__global__ __launch_bounds__(256) void gemm_f32(
    const float* __restrict__ A, int lda,
    const void* __restrict__ Bw, size_t bwo, int ldb,
    float* __restrict__ C, int ldc,
    int Kd,
    const void* __restrict__ bias, size_t biaso,
    const float* __restrict__ resid,
    const float* __restrict__ flagp)
{
    const bool isbf = (*flagp > 0.5f);
    __shared__ float As[16][64];   // As[k][m]
    __shared__ float Bs[16][64];   // Bs[k][n]
    const int tid = threadIdx.x;
    const int tx = tid & 15, ty = tid >> 4;
    const int m0 = blockIdx.y << 6, n0 = blockIdx.x << 6;
    const int la_m = tid >> 2, la_k = (tid & 3) << 2;   // A: 64 rows x 16 cols, float4/thread
    const int lb_k = tid >> 4, lb_n = (tid & 15) << 2;  // B: 16 rows x 64 cols, 4 elems/thread
    float acc[4][4] = {};

    for (int k0 = 0; k0 < Kd; k0 += 16) {
        const float4 av = *(const float4*)&A[(size_t)(m0 + la_m) * lda + k0 + la_k];
        const F4 bv = load4(Bw, bwo + (size_t)(k0 + lb_k) * ldb + n0 + lb_n, isbf);
        __syncthreads();
        As[la_k + 0][la_m] = av.x; As[la_k + 1][la_m] = av.y;
        As[la_k + 2][la_m] = av.z; As[la_k + 3][la_m] = av.w;
        Bs[lb_k][lb_n + 0] = bv.x; Bs[lb_k][lb_n + 1] = bv.y;
        Bs[lb_k][lb_n + 2] = bv.z; Bs[lb_k][lb_n + 3] = bv.w;
        __syncthreads();
        #pragma unroll
        for (int k = 0; k < 16; k++) {
            const float4 a = *(const float4*)&As[k][ty << 2];
            const float4 b = *(const float4*)&Bs[k][tx << 2];
            acc[0][0] = fmaf(a.x, b.x, acc[0][0]); acc[0][1] = fmaf(a.x, b.y, acc[0][1]);
            acc[0][2] = fmaf(a.x, b.z, acc[0][2]); acc[0][3] = fmaf(a.x, b.w, acc[0][3]);
            acc[1][0] = fmaf(a.y, b.x, acc[1][0]); acc[1][1] = fmaf(a.y, b.y, acc[1][1]);
            acc[1][2] = fmaf(a.y, b.z, acc[1][2]); acc[1][3] = fmaf(a.y, b.w, acc[1][3]);
            acc[2][0] = fmaf(a.z, b.x, acc[2][0]); acc[2][1] = fmaf(a.z, b.y, acc[2][1]);
            acc[2][2] = fmaf(a.z, b.z, acc[2][2]); acc[2][3] = fmaf(a.z, b.w, acc[2][3]);
            acc[3][0] = fmaf(a.w, b.x, acc[3][0]); acc[3][1] = fmaf(a.w, b.y, acc[3][1]);
            acc[3][2] = fmaf(a.w, b.z, acc[3][2]); acc[3][3] = fmaf(a.w, b.w, acc[3][3]);
        }
    }
    #pragma unroll
    for (int i = 0; i < 4; i++) {
        const int row = m0 + (ty << 2) + i;
        const int col = n0 + (tx << 2);
        float v[4];
        #pragma unroll
        for (int j = 0; j < 4; j++) {
            float t = acc[i][j];
            if (EP == 1) { t += load1(bias, biaso + col + j, isbf);
                           t = (t > 20.f) ? t : log1pf(expf(t)); }
            if (EP == 2) { t += resid[(size_t)row * ldc + col + j]; }
            v[j] = t;
        }
        *(float4*)&C[(size_t)row * ldc + col] = make_float4(v[0], v[1], v[2], v[3]);
    }
}

// ---------------- depthwise causal conv(4) + bias + SiLU ----------------
__global__ __launch_bounds__(256) void conv_silu(
    const float* __restrict__ xz, const void* __restrict__ cw, size_t cwo,
    const void* __restrict__ cb, size_t cbo, float* __restrict__ xc,
    const float* __restrict__ flagp)
{
    const bool isbf = (*flagp > 0.5f);
    const int idx = blockIdx.x * 256 + threadIdx.x;     // over 4096*1024
    const int d = idx & (DI - 1);
    const int row = idx >> 10;
    const int l = row & (L_ - 1);
    const F4 wv = load4(cw, cwo + (size_t)d * 4, isbf);
    const float* base = xz + (size_t)row * 2048 + d;
    float acc = load1(cb, cbo + d, isbf) + wv.w * base[0];
    if (l >= 1) acc += wv.z * base[-2048];
    if (l >= 2) acc += wv.y * base[-4096];
    if (l >= 3) acc += wv.x * base[-6144];
    xc[idx] = silu_(acc);
}

// ---------------- scan phase 1: per-chunk local scan + sum(dt) summary ----------------
__global__ __launch_bounds__(256) void scan_phase1(
    const float* __restrict__ dtb, const float* __restrict__ xcb,
    const float* __restrict__ dbc, const void* __restrict__ Alog, size_t alo,
    float* __restrict__ Sdt, float* __restrict__ Sbuf,
    const float* __restrict__ flagp)
{
    const bool isbf = (*flagp > 0.5f);
    __shared__ float sB[CH][16];
    const int blk = blockIdx.x;
    const int dblk = blk & 3;
    const int c = (blk >> 2) & (NC - 1);
    const int b = blk >> 7;
    const int d = dblk * 256 + threadIdx.x;
    const int row0 = b * L_ + c * CH;
    {   // stage B-chunk (64 x 16) into LDS
        const int l = threadIdx.x >> 2, s4 = (threadIdx.x & 3) << 2;
        *(float4*)&sB[l][s4] = *(const float4*)&dbc[(size_t)(row0 + l) * 64 + 32 + s4];
    }
    __syncthreads();
    float A[DS];
    #pragma unroll
    for (int s = 0; s < DS; s++) A[s] = -expf(load1(Alog, alo + (size_t)d * DS + s, isbf));
    float h[DS];
    #pragma unroll
    for (int s = 0; s < DS; s++) h[s] = 0.f;
    float sdt = 0.f;
    for (int l = 0; l < CH; l++) {
        const int row = row0 + l;
        const float dtv = dtb[(size_t)row * DI + d];
        const float xv  = xcb[(size_t)row * DI + d];
        sdt += dtv;
        const float dtx = dtv * xv;
        #pragma unroll
        for (int s = 0; s < DS; s++) {
            const float dA = expf(dtv * A[s]);
            h[s] = fmaf(dA, h[s], dtx * sB[l][s]);
        }
    }
    const int cb_ = b * NC + c;
    Sdt[(size_t)cb_ * DI + d] = sdt;
    #pragma unroll
    for (int s = 0; s < DS; s++) Sbuf[((size_t)cb_ * DS + s) * DI + d] = h[s];
}

// ---------------- scan phase 2: exclusive scan over chunk summaries ----------------
__global__ __launch_bounds__(256) void scan_phase2(
    const float* __restrict__ Sdt, const float* __restrict__ Sbuf,
    const void* __restrict__ Alog, size_t alo, float* __restrict__ H0,
    const float* __restrict__ flagp)
{
    const bool isbf = (*flagp > 0.5f);
    const int g = blockIdx.x * 256 + threadIdx.x;   // 2*16*1024 = 32768 threads
    const int d = g & (DI - 1);
    const int s = (g >> 10) & (DS - 1);
    const int b = g >> 14;
    const float A = -expf(load1(Alog, alo + (size_t)d * DS + s, isbf));
    float h = 0.f;
    for (int c = 0; c < NC; c++) {
        const int cb_ = b * NC + c;
        H0[((size_t)cb_ * DS + s) * DI + d] = h;
        const float P = expf(A * Sdt[(size_t)cb_ * DI + d]);
        h = fmaf(P, h, Sbuf[((size_t)cb_ * DS + s) * DI + d]);
    }
}

// ---------------- scan phase 3: replay chunk with true init, fuse y/D/z-gate ----------------
__global__ __launch_bounds__(256) void scan_phase3(
    const float* __restrict__ dtb, float* __restrict__ xcb,
    const float* __restrict__ dbc, const void* __restrict__ Alog, size_t alo,
    const float* __restrict__ H0, const void* __restrict__ Dpv, size_t dpo,
    const float* __restrict__ xz, const float* __restrict__ flagp)
{
    const bool isbf = (*flagp > 0.5f);
    __shared__ float sBC[CH][32];
    const int blk = blockIdx.x;
    const int dblk = blk & 3;
    const int c = (blk >> 2) & (NC - 1);
    const int b = blk >> 7;
    const int d = dblk * 256 + threadIdx.x;
    const int row0 = b * L_ + c * CH;
    {   // stage B and C chunk (64 x 32) into LDS
        const int l = threadIdx.x >> 2, q = (threadIdx.x & 3) << 3;
        *(float4*)&sBC[l][q]     = *(const float4*)&dbc[(size_t)(row0 + l) * 64 + 32 + q];
        *(float4*)&sBC[l][q + 4] = *(const float4*)&dbc[(size_t)(row0 + l) * 64 + 36 + q];
    }
    __syncthreads();
    float A[DS];
    #pragma unroll
    for (int s = 0; s < DS; s++) A[s] = -expf(load1(Alog, alo + (size_t)d * DS + s, isbf));
    const int cb_ = b * NC + c;
    float h[DS];
    #pragma unroll
    for (int s = 0; s < DS; s++) h[s] = H0[((size_t)cb_ * DS + s) * DI + d];
    const float Dpd = load1(Dpv, dpo + d, isbf);
    for (int l = 0; l < CH; l++) {
        const int row = row0 + l;
        const float dtv = dtb[(size_t)row * DI + d];
        const float xv  = xcb[(size_t)row * DI + d];
        const float dtx = dtv * xv;
        float y = 0.f;
        #pragma unroll
        for (int s = 0; s < DS; s++) {
            const float dA = expf(dtv * A[s]);
            h[s] = fmaf(dA, h[s], dtx * sBC[l][s]);
            y = fmaf(h[s], sBC[l][16 + s], y);
        }
        y = fmaf(xv, Dpd, y);
        const float zv = xz[(size_t)row * 2048 + DI + d];
        y *= silu_(zv);
        xcb[(size_t)row * DI + d] = y;   // in-place: xc buffer becomes y
    }
}

// ---------------- dtype casts ----------------
__global__ void cast_in(const void* __restrict__ in, float* __restrict__ out, int n,
                        const float* __restrict__ flagp) {
    const bool isbf = (*flagp > 0.5f);
    const int i = blockIdx.x * 256 + threadIdx.x;
    if (i < n) out[i] = load1(in, (size_t)i, isbf);
}
__global__ void cast_out(const float* __restrict__ in, void* __restrict__ out, int n,
                         const float* __restrict__ flagp) {
    const bool isbf = (*flagp > 0.5f);
    const int i = blockIdx.x * 256 + threadIdx.x;
    if (i < n) {
        if (isbf) ((u16*)out)[i] = f2b(in[i]);
        else      ((float*)out)[i] = in[i];
    }
}

extern "C" void kernel_launch(void* const* d_in, const int* in_sizes, int n_in,
                              void* d_out, int out_size, void* d_ws, size_t ws_size,
                              hipStream_t stream)
{
    const void* x_in  = d_in[0];
    const void* W_in  = d_in[1];
    const void* convw = d_in[2];
    const void* convb = d_in[3];
    const void* W_x   = d_in[4];
    const void* W_dt  = d_in[5];
    const void* b_dt  = d_in[6];
    const void* A_log = d_in[7];
    const void* Dp    = d_in[8];
    const void* W_out = d_in[9];

    float* ws = (float*)d_ws;
    float* flag = ws;                               // 4 floats (alignment pad)
    float* xz   = ws + 4;                           // 4096*2048
    float* xc   = xz  + (size_t)MROWS * 2048;       // 4096*1024 (y in-place after phase3)
    float* dbc  = xc  + (size_t)MROWS * DI;         // 4096*64
    float* dtb  = dbc + (size_t)MROWS * 64;         // 4096*1024
    float* Sdt  = dtb + (size_t)MROWS * DI;         // 2*32*1024
    float* Sbuf = Sdt + (size_t)2 * NC * DI;        // 2*32*16*1024
    float* H0   = Sbuf + (size_t)2 * NC * DS * DI;  // 2*32*16*1024
    float* xb0  = H0  + (size_t)2 * NC * DS * DI;   // 4096*512
    float* xb1  = xb0 + (size_t)MROWS * DM;         // 4096*512

    probe_dtype<<<1, 256, 0, stream>>>(x_in, flag);
    cast_in<<<(MROWS * DM) / 256, 256, 0, stream>>>(x_in, xb0, MROWS * DM, flag);

    const float* xcur = xb0;
    for (int i = 0; i < NBLK; i++) {
        float* xnext = (i & 1) ? xb0 : xb1;
        // xz = x @ W_in  (4096 x 2048 x 512)
        gemm_f32<0><<<dim3(2048 / 64, MROWS / 64), 256, 0, stream>>>(
            xcur, DM, W_in, (size_t)i * DM * 2048, 2048, xz, 2048, DM, nullptr, 0, nullptr, flag);
        // xc = silu(conv(xi) + cb)
        conv_silu<<<(MROWS * DI) / 256, 256, 0, stream>>>(
            xz, convw, (size_t)i * DI * 4, convb, (size_t)i * DI, xc, flag);
        // dbc = xc @ W_x  (4096 x 64 x 1024)
        gemm_f32<0><<<dim3(1, MROWS / 64), 256, 0, stream>>>(
            xc, DI, W_x, (size_t)i * DI * 64, 64, dbc, 64, DI, nullptr, 0, nullptr, flag);
        // dt = softplus(dt_raw @ W_dt + b_dt)  (4096 x 1024 x 32)
        gemm_f32<1><<<dim3(DI / 64, MROWS / 64), 256, 0, stream>>>(
            dbc, 64, W_dt, (size_t)i * 32 * DI, DI, dtb, DI, 32, b_dt, (size_t)i * DI, nullptr, flag);
        // selective scan (3-phase chunked)
        scan_phase1<<<256, 256, 0, stream>>>(dtb, xc, dbc, A_log, (size_t)i * DI * DS, Sdt, Sbuf, flag);
        scan_phase2<<<128, 256, 0, stream>>>(Sdt, Sbuf, A_log, (size_t)i * DI * DS, H0, flag);
        scan_phase3<<<256, 256, 0, stream>>>(dtb, xc, dbc, A_log, (size_t)i * DI * DS, H0,
                                             Dp, (size_t)i * DI, xz, flag);
        // out = y @ W_out + resid  (4096 x 512 x 1024)
        gemm_f32<2><<<dim3(DM / 64, MROWS / 64), 256, 0, stream>>>(
            xc, DI, W_out, (size_t)i * DI * DM, DM, xnext, DM, DI, nullptr, 0, xcur, flag);
        xcur = xnext;
    }
    cast_out<<<(MROWS * DM) / 256, 256, 0, stream>>>(xcur, d_out, MROWS * DM, flag);
}

// Round 5
// 1346.893 us; speedup vs baseline: 1.3477x; 1.3477x over previous
//
#include <hip/hip_runtime.h>

// MambaEncoder: B=2, L=2048, D_MODEL=512, D_INNER=1024, DT_RANK=32, D_STATE=16, 4 blocks.
// Round 5: inputs are genuinely FP32 (proven by r1-vs-r2 bisect: hard-coded bf16 NaN'd,
// runtime-dispatch passed => probe took fp32 path). r2 code kept verbatim; gemm_mfma now
// converts BOTH A (fp32 ws) and B (flag-dispatched input dtype) to bf16 during LDS staging,
// accumulates fp32 in MFMA. Used for GEMM1/GEMM2/GEMM3; dt-GEMM stays fp32 VALU (verified).

#define L_    2048
#define DM    512
#define DI    1024
#define DS    16
#define NBLK  4
#define NC    32
#define CH    64
#define MROWS 4096   // B_ * L_

using u16 = unsigned short;
typedef __bf16 bf16x8 __attribute__((ext_vector_type(8)));
typedef float  f32x4  __attribute__((ext_vector_type(4)));

__device__ __forceinline__ float b2f(u16 u) {
    union { unsigned int i; float f; } v; v.i = ((unsigned int)u) << 16; return v.f;
}
__device__ __forceinline__ u16 f2b(float f) {
    union { float f; unsigned int i; } v; v.f = f;
    unsigned int x = v.i;
    return (u16)((x + 0x7FFFu + ((x >> 16) & 1u)) >> 16);
}
__device__ __forceinline__ float silu_(float x) { return x / (1.f + expf(-x)); }

struct F4 { float x, y, z, w; };
__device__ __forceinline__ F4 load4(const void* p, size_t e, bool isbf) {
    F4 r;
    if (isbf) {
        ushort4 v = *(const ushort4*)((const u16*)p + e);
        r.x = b2f(v.x); r.y = b2f(v.y); r.z = b2f(v.z); r.w = b2f(v.w);
    } else {
        float4 v = *(const float4*)((const float*)p + e);
        r.x = v.x; r.y = v.y; r.z = v.z; r.w = v.w;
    }
    return r;
}
__device__ __forceinline__ float load1(const void* p, size_t e, bool isbf) {
    return isbf ? b2f(((const u16*)p)[e]) : ((const float*)p)[e];
}

// ---------------- dtype probe (round-2 verbatim) ----------------
__global__ void probe_dtype(const void* x, float* flag) {
    __shared__ int allok;
    if (threadIdx.x == 0) allok = 1;
    __syncthreads();
    const u16* p = (const u16*)x;
    bool ok = true;
    for (int i = threadIdx.x; i < 65536; i += 256) {
        float v = b2f(p[i]);
        if (!(v == v) || fabsf(v) >= 1000.f) ok = false;
    }
    if (!ok) allok = 0;
    __syncthreads();
    if (threadIdx.x == 0) flag[0] = allok ? 1.f : 0.f;
}

// ---------------- fp32 VALU GEMM (round-2 verbatim; used for dt GEMM only) ----------------
template<int EP>
__global__ __launch_bounds__(256) void gemm_f32(
    const float* __restrict__ A, int lda,
    const void* __restrict__ Bw, size_t bwo, int ldb,
    float* __restrict__ C, int ldc,
    int Kd,
    const void* __restrict__ bias, size_t biaso,
    const float* __restrict__ resid,
    const float* __restrict__ flagp)
{
    const bool isbf = (*flagp > 0.5f);
    __shared__ float As[16][64];
    __shared__ float Bs[16][64];
    const int tid = threadIdx.x;
    const int tx = tid & 15, ty = tid >> 4;
    const int m0 = blockIdx.y << 6, n0 = blockIdx.x << 6;
    const int la_m = tid >> 2, la_k = (tid & 3) << 2;
    const int lb_k = tid >> 4, lb_n = (tid & 15) << 2;
    float acc[4][4] = {};

    for (int k0 = 0; k0 < Kd; k0 += 16) {
        const float4 av = *(const float4*)&A[(size_t)(m0 + la_m) * lda + k0 + la_k];
        const F4 bv = load4(Bw, bwo + (size_t)(k0 + lb_k) * ldb + n0 + lb_n, isbf);
        __syncthreads();
        As[la_k + 0][la_m] = av.x; As[la_k + 1][la_m] = av.y;
        As[la_k + 2][la_m] = av.z; As[la_k + 3][la_m] = av.w;
        Bs[lb_k][lb_n + 0] = bv.x; Bs[lb_k][lb_n + 1] = bv.y;
        Bs[lb_k][lb_n + 2] = bv.z; Bs[lb_k][lb_n + 3] = bv.w;
        __syncthreads();
        #pragma unroll
        for (int k = 0; k < 16; k++) {
            const float4 a = *(const float4*)&As[k][ty << 2];
            const float4 b = *(const float4*)&Bs[k][tx << 2];
            acc[0][0] = fmaf(a.x, b.x, acc[0][0]); acc[0][1] = fmaf(a.x, b.y, acc[0][1]);
            acc[0][2] = fmaf(a.x, b.z, acc[0][2]); acc[0][3] = fmaf(a.x, b.w, acc[0][3]);
            acc[1][0] = fmaf(a.y, b.x, acc[1][0]); acc[1][1] = fmaf(a.y, b.y, acc[1][1]);
            acc[1][2] = fmaf(a.y, b.z, acc[1][2]); acc[1][3] = fmaf(a.y, b.w, acc[1][3]);
            acc[2][0] = fmaf(a.z, b.x, acc[2][0]); acc[2][1] = fmaf(a.z, b.y, acc[2][1]);
            acc[2][2] = fmaf(a.z, b.z, acc[2][2]); acc[2][3] = fmaf(a.z, b.w, acc[2][3]);
            acc[3][0] = fmaf(a.w, b.x, acc[3][0]); acc[3][1] = fmaf(a.w, b.y, acc[3][1]);
            acc[3][2] = fmaf(a.w, b.z, acc[3][2]); acc[3][3] = fmaf(a.w, b.w, acc[3][3]);
        }
    }
    #pragma unroll
    for (int i = 0; i < 4; i++) {
        const int row = m0 + (ty << 2) + i;
        const int col = n0 + (tx << 2);
        float v[4];
        #pragma unroll
        for (int j = 0; j < 4; j++) {
            float t = acc[i][j];
            if (EP == 1) { t += load1(bias, biaso + col + j, isbf);
                           t = (t > 20.f) ? t : log1pf(expf(t)); }
            if (EP == 2) { t += resid[(size_t)row * ldc + col + j]; }
            v[j] = t;
        }
        *(float4*)&C[(size_t)row * ldc + col] = make_float4(v[0], v[1], v[2], v[3]);
    }
}

// ---------------- MFMA GEMM: C(fp32)[M][N] = A(fp32)[M][K] @ B(flag dtype)[K][N] ----------------
// BM=128, BK=32, 256 threads = 4 waves (2x2). A fp32->bf16 in staging; B loaded via load4
// (honors fp32/bf16 flag), converted bf16, transposed into LDS [n][k]. fp32 accumulate.
template<int BN, int EP>
__global__ __launch_bounds__(256) void gemm_mfma(
    const float* __restrict__ A, int lda,
    const void* __restrict__ Bg, size_t bgo, int ldb,   // [K][N] row-major, input dtype
    float* __restrict__ C, int ldc,
    int Kd,
    const float* __restrict__ resid,
    const float* __restrict__ flagp)
{
    const bool isbf = (*flagp > 0.5f);
    constexpr int NT = BN / 32;            // n-tiles per wave
    __shared__ u16 sA[128][40];            // [m][k], +8 pad
    __shared__ u16 sB[BN][40];             // [n][k]
    const int tid = threadIdx.x;
    const int lane = tid & 63;
    const int wid = tid >> 6;
    const int wm = wid >> 1, wn = wid & 1;
    const int m0 = blockIdx.y << 7;
    const int n0 = blockIdx.x * BN;
    const int col16 = lane & 15, quad = lane >> 4;

    f32x4 acc[4][NT];
    #pragma unroll
    for (int i = 0; i < 4; i++)
        #pragma unroll
        for (int j = 0; j < NT; j++) acc[i][j] = {0.f, 0.f, 0.f, 0.f};

    for (int k0 = 0; k0 < Kd; k0 += 32) {
        // A: 128 rows x 32 cols fp32. 512 slots, 2 per thread, 8 floats each.
        float4 f[2][2];
        #pragma unroll
        for (int it = 0; it < 2; it++) {
            const int slot = tid + it * 256;
            const int ar = slot >> 2, ac = (slot & 3) << 3;
            f[it][0] = *(const float4*)&A[(size_t)(m0 + ar) * lda + k0 + ac];
            f[it][1] = *(const float4*)&A[(size_t)(m0 + ar) * lda + k0 + ac + 4];
        }
        // B: 32 k-rows x BN n-cols, dtype-dispatched load, transpose into sB[n][k].
        F4 bv[BN / 32];
        int bn4[BN / 32], bkk[BN / 32];
        #pragma unroll
        for (int it = 0; it < BN / 32; it++) {
            const int slot = tid + it * 256;
            bkk[it] = slot & 31;
            bn4[it] = (slot >> 5) << 2;
            bv[it] = load4(Bg, bgo + (size_t)(k0 + bkk[it]) * ldb + n0 + bn4[it], isbf);
        }
        __syncthreads();
        #pragma unroll
        for (int it = 0; it < 2; it++) {
            const int slot = tid + it * 256;
            const int ar = slot >> 2, ac = (slot & 3) << 3;
            ushort4 lo = make_ushort4(f2b(f[it][0].x), f2b(f[it][0].y), f2b(f[it][0].z), f2b(f[it][0].w));
            ushort4 hi = make_ushort4(f2b(f[it][1].x), f2b(f[it][1].y), f2b(f[it][1].z), f2b(f[it][1].w));
            *(ushort4*)&sA[ar][ac] = lo;
            *(ushort4*)&sA[ar][ac + 4] = hi;
        }
        #pragma unroll
        for (int it = 0; it < BN / 32; it++) {
            sB[bn4[it] + 0][bkk[it]] = f2b(bv[it].x);
            sB[bn4[it] + 1][bkk[it]] = f2b(bv[it].y);
            sB[bn4[it] + 2][bkk[it]] = f2b(bv[it].z);
            sB[bn4[it] + 3][bkk[it]] = f2b(bv[it].w);
        }
        __syncthreads();
        // fragments: A[m = lane&15][k = quad*8+j], B[n = lane&15][k = quad*8+j]
        bf16x8 af[4], bfr[NT];
        #pragma unroll
        for (int mi = 0; mi < 4; mi++)
            af[mi] = *(const bf16x8*)&sA[wm * 64 + mi * 16 + col16][quad * 8];
        #pragma unroll
        for (int ni = 0; ni < NT; ni++)
            bfr[ni] = *(const bf16x8*)&sB[wn * (BN / 2) + ni * 16 + col16][quad * 8];
        #pragma unroll
        for (int mi = 0; mi < 4; mi++)
            #pragma unroll
            for (int ni = 0; ni < NT; ni++)
                acc[mi][ni] = __builtin_amdgcn_mfma_f32_16x16x32_bf16(
                    af[mi], bfr[ni], acc[mi][ni], 0, 0, 0);
    }
    // epilogue: C/D layout col = lane&15, row = quad*4 + reg  [m89/m91 verified]
    #pragma unroll
    for (int mi = 0; mi < 4; mi++) {
        #pragma unroll
        for (int ni = 0; ni < NT; ni++) {
            #pragma unroll
            for (int rr = 0; rr < 4; rr++) {
                const int row = m0 + wm * 64 + mi * 16 + quad * 4 + rr;
                const int col = n0 + wn * (BN / 2) + ni * 16 + col16;
                float t = acc[mi][ni][rr];
                if (EP == 2) t += resid[(size_t)row * ldc + col];
                C[(size_t)row * ldc + col] = t;
            }
        }
    }
}

// ---------------- conv / scans / casts (round-2 verbatim) ----------------
__global__ __launch_bounds__(256) void conv_silu(
    const float* __restrict__ xz, const void* __restrict__ cw, size_t cwo,
    const void* __restrict__ cb, size_t cbo, float* __restrict__ xc,
    const float* __restrict__ flagp)
{
    const bool isbf = (*flagp > 0.5f);
    const int idx = blockIdx.x * 256 + threadIdx.x;
    const int d = idx & (DI - 1);
    const int row = idx >> 10;
    const int l = row & (L_ - 1);
    const F4 wv = load4(cw, cwo + (size_t)d * 4, isbf);
    const float* base = xz + (size_t)row * 2048 + d;
    float acc = load1(cb, cbo + d, isbf) + wv.w * base[0];
    if (l >= 1) acc += wv.z * base[-2048];
    if (l >= 2) acc += wv.y * base[-4096];
    if (l >= 3) acc += wv.x * base[-6144];
    xc[idx] = silu_(acc);
}

__global__ __launch_bounds__(256) void scan_phase1(
    const float* __restrict__ dtb, const float* __restrict__ xcb,
    const float* __restrict__ dbc, const void* __restrict__ Alog, size_t alo,
    float* __restrict__ Sdt, float* __restrict__ Sbuf,
    const float* __restrict__ flagp)
{
    const bool isbf = (*flagp > 0.5f);
    __shared__ float sB[CH][16];
    const int blk = blockIdx.x;
    const int dblk = blk & 3;
    const int c = (blk >> 2) & (NC - 1);
    const int b = blk >> 7;
    const int d = dblk * 256 + threadIdx.x;
    const int row0 = b * L_ + c * CH;
    {
        const int l = threadIdx.x >> 2, s4 = (threadIdx.x & 3) << 2;
        *(float4*)&sB[l][s4] = *(const float4*)&dbc[(size_t)(row0 + l) * 64 + 32 + s4];
    }
    __syncthreads();
    float A[DS];
    #pragma unroll
    for (int s = 0; s < DS; s++) A[s] = -expf(load1(Alog, alo + (size_t)d * DS + s, isbf));
    float h[DS];
    #pragma unroll
    for (int s = 0; s < DS; s++) h[s] = 0.f;
    float sdt = 0.f;
    for (int l = 0; l < CH; l++) {
        const int row = row0 + l;
        const float dtv = dtb[(size_t)row * DI + d];
        const float xv  = xcb[(size_t)row * DI + d];
        sdt += dtv;
        const float dtx = dtv * xv;
        #pragma unroll
        for (int s = 0; s < DS; s++) {
            const float dA = expf(dtv * A[s]);
            h[s] = fmaf(dA, h[s], dtx * sB[l][s]);
        }
    }
    const int cb_ = b * NC + c;
    Sdt[(size_t)cb_ * DI + d] = sdt;
    #pragma unroll
    for (int s = 0; s < DS; s++) Sbuf[((size_t)cb_ * DS + s) * DI + d] = h[s];
}

__global__ __launch_bounds__(256) void scan_phase2(
    const float* __restrict__ Sdt, const float* __restrict__ Sbuf,
    const void* __restrict__ Alog, size_t alo, float* __restrict__ H0,
    const float* __restrict__ flagp)
{
    const bool isbf = (*flagp > 0.5f);
    const int g = blockIdx.x * 256 + threadIdx.x;
    const int d = g & (DI - 1);
    const int s = (g >> 10) & (DS - 1);
    const int b = g >> 14;
    const float A = -expf(load1(Alog, alo + (size_t)d * DS + s, isbf));
    float h = 0.f;
    for (int c = 0; c < NC; c++) {
        const int cb_ = b * NC + c;
        H0[((size_t)cb_ * DS + s) * DI + d] = h;
        const float P = expf(A * Sdt[(size_t)cb_ * DI + d]);
        h = fmaf(P, h, Sbuf[((size_t)cb_ * DS + s) * DI + d]);
    }
}

__global__ __launch_bounds__(256) void scan_phase3(
    const float* __restrict__ dtb, float* __restrict__ xcb,
    const float* __restrict__ dbc, const void* __restrict__ Alog, size_t alo,
    const float* __restrict__ H0, const void* __restrict__ Dpv, size_t dpo,
    const float* __restrict__ xz, const float* __restrict__ flagp)
{
    const bool isbf = (*flagp > 0.5f);
    __shared__ float sBC[CH][32];
    const int blk = blockIdx.x;
    const int dblk = blk & 3;
    const int c = (blk >> 2) & (NC - 1);
    const int b = blk >> 7;
    const int d = dblk * 256 + threadIdx.x;
    const int row0 = b * L_ + c * CH;
    {
        const int l = threadIdx.x >> 2, q = (threadIdx.x & 3) << 3;
        *(float4*)&sBC[l][q]     = *(const float4*)&dbc[(size_t)(row0 + l) * 64 + 32 + q];
        *(float4*)&sBC[l][q + 4] = *(const float4*)&dbc[(size_t)(row0 + l) * 64 + 36 + q];
    }
    __syncthreads();
    float A[DS];
    #pragma unroll
    for (int s = 0; s < DS; s++) A[s] = -expf(load1(Alog, alo + (size_t)d * DS + s, isbf));
    const int cb_ = b * NC + c;
    float h[DS];
    #pragma unroll
    for (int s = 0; s < DS; s++) h[s] = H0[((size_t)cb_ * DS + s) * DI + d];
    const float Dpd = load1(Dpv, dpo + d, isbf);
    for (int l = 0; l < CH; l++) {
        const int row = row0 + l;
        const float dtv = dtb[(size_t)row * DI + d];
        const float xv  = xcb[(size_t)row * DI + d];
        const float dtx = dtv * xv;
        float y = 0.f;
        #pragma unroll
        for (int s = 0; s < DS; s++) {
            const float dA = expf(dtv * A[s]);
            h[s] = fmaf(dA, h[s], dtx * sBC[l][s]);
            y = fmaf(h[s], sBC[l][16 + s], y);
        }
        y = fmaf(xv, Dpd, y);
        const float zv = xz[(size_t)row * 2048 + DI + d];
        y *= silu_(zv);
        xcb[(size_t)row * DI + d] = y;
    }
}

__global__ void cast_in(const void* __restrict__ in, float* __restrict__ out, int n,
                        const float* __restrict__ flagp) {
    const bool isbf = (*flagp > 0.5f);
    const int i = blockIdx.x * 256 + threadIdx.x;
    if (i < n) out[i] = load1(in, (size_t)i, isbf);
}
__global__ void cast_out(const float* __restrict__ in, void* __restrict__ out, int n,
                         const float* __restrict__ flagp) {
    const bool isbf = (*flagp > 0.5f);
    const int i = blockIdx.x * 256 + threadIdx.x;
    if (i < n) {
        if (isbf) ((u16*)out)[i] = f2b(in[i]);
        else      ((float*)out)[i] = in[i];
    }
}

extern "C" void kernel_launch(void* const* d_in, const int* in_sizes, int n_in,
                              void* d_out, int out_size, void* d_ws, size_t ws_size,
                              hipStream_t stream)
{
    const void* x_in  = d_in[0];
    const void* W_in  = d_in[1];
    const void* convw = d_in[2];
    const void* convb = d_in[3];
    const void* W_x   = d_in[4];
    const void* W_dt  = d_in[5];
    const void* b_dt  = d_in[6];
    const void* A_log = d_in[7];
    const void* Dp    = d_in[8];
    const void* W_out = d_in[9];

    float* ws = (float*)d_ws;
    float* flag = ws;
    float* xz   = ws + 4;
    float* xc   = xz  + (size_t)MROWS * 2048;
    float* dbc  = xc  + (size_t)MROWS * DI;
    float* dtb  = dbc + (size_t)MROWS * 64;
    float* Sdt  = dtb + (size_t)MROWS * DI;
    float* Sbuf = Sdt + (size_t)2 * NC * DI;
    float* H0   = Sbuf + (size_t)2 * NC * DS * DI;
    float* xb0  = H0  + (size_t)2 * NC * DS * DI;
    float* xb1  = xb0 + (size_t)MROWS * DM;

    probe_dtype<<<1, 256, 0, stream>>>(x_in, flag);
    cast_in<<<(MROWS * DM) / 256, 256, 0, stream>>>(x_in, xb0, MROWS * DM, flag);

    const float* xcur = xb0;
    for (int i = 0; i < NBLK; i++) {
        float* xnext = (i & 1) ? xb0 : xb1;
        // xz = x @ W_in  (4096 x 2048, K=512) -- MFMA
        gemm_mfma<128, 0><<<dim3(2048 / 128, MROWS / 128), 256, 0, stream>>>(
            xcur, DM, W_in, (size_t)i * DM * 2048, 2048, xz, 2048, DM, nullptr, flag);
        // xc = silu(conv(xi) + cb)
        conv_silu<<<(MROWS * DI) / 256, 256, 0, stream>>>(
            xz, convw, (size_t)i * DI * 4, convb, (size_t)i * DI, xc, flag);
        // dbc = xc @ W_x  (4096 x 64, K=1024) -- MFMA
        gemm_mfma<64, 0><<<dim3(1, MROWS / 128), 256, 0, stream>>>(
            xc, DI, W_x, (size_t)i * DI * 64, 64, dbc, 64, DI, nullptr, flag);
        // dt = softplus(dt_raw @ W_dt + b_dt)  (4096 x 1024, K=32) -- fp32 VALU (verified)
        gemm_f32<1><<<dim3(DI / 64, MROWS / 64), 256, 0, stream>>>(
            dbc, 64, W_dt, (size_t)i * 32 * DI, DI, dtb, DI, 32, b_dt, (size_t)i * DI, nullptr, flag);
        // selective scan (3-phase chunked)
        scan_phase1<<<256, 256, 0, stream>>>(dtb, xc, dbc, A_log, (size_t)i * DI * DS, Sdt, Sbuf, flag);
        scan_phase2<<<128, 256, 0, stream>>>(Sdt, Sbuf, A_log, (size_t)i * DI * DS, H0, flag);
        scan_phase3<<<256, 256, 0, stream>>>(dtb, xc, dbc, A_log, (size_t)i * DI * DS, H0,
                                             Dp, (size_t)i * DI, xz, flag);
        // out = y @ W_out + resid  (4096 x 512, K=1024) -- MFMA
        gemm_mfma<128, 2><<<dim3(DM / 128, MROWS / 128), 256, 0, stream>>>(
            xc, DI, W_out, (size_t)i * DI * DM, DM, xnext, DM, DI, xcur, flag);
        xcur = xnext;
    }
    cast_out<<<(MROWS * DM) / 256, 256, 0, stream>>>(xcur, d_out, MROWS * DM, flag);
}

// Round 6
// 1205.656 us; speedup vs baseline: 1.5055x; 1.1171x over previous
//
#include <hip/hip_runtime.h>

// MambaEncoder: B=2, L=2048, D_MODEL=512, D_INNER=1024, DT_RANK=32, D_STATE=16, 4 blocks.
// Round 6 (from r5 pass @1347us): (1) probe samples 2048 not 65536 (-100us);
// (2) scan NC=128/CH=16 -> 1024 blocks (occupancy 10%->~35%), phase2 in-place in Sbuf (no H0);
// (3) gemm_mfma gains MT template (BM=32 for GEMM2 -> 128 blocks); (4) single x buffer
// (GEMM3 residual add is element-wise in-place safe). ws ~= 94 MB (r2 proved >= 93.6 MB).

#define L_    2048
#define DM    512
#define DI    1024
#define DS    16
#define NBLK  4
#define NC    128
#define CH    16
#define MROWS 4096   // B_ * L_

using u16 = unsigned short;
typedef __bf16 bf16x8 __attribute__((ext_vector_type(8)));
typedef float  f32x4  __attribute__((ext_vector_type(4)));

__device__ __forceinline__ float b2f(u16 u) {
    union { unsigned int i; float f; } v; v.i = ((unsigned int)u) << 16; return v.f;
}
__device__ __forceinline__ u16 f2b(float f) {
    union { float f; unsigned int i; } v; v.f = f;
    unsigned int x = v.i;
    return (u16)((x + 0x7FFFu + ((x >> 16) & 1u)) >> 16);
}
__device__ __forceinline__ float silu_(float x) { return x / (1.f + expf(-x)); }

struct F4 { float x, y, z, w; };
__device__ __forceinline__ F4 load4(const void* p, size_t e, bool isbf) {
    F4 r;
    if (isbf) {
        ushort4 v = *(const ushort4*)((const u16*)p + e);
        r.x = b2f(v.x); r.y = b2f(v.y); r.z = b2f(v.z); r.w = b2f(v.w);
    } else {
        float4 v = *(const float4*)((const float*)p + e);
        r.x = v.x; r.y = v.y; r.z = v.z; r.w = v.w;
    }
    return r;
}
__device__ __forceinline__ float load1(const void* p, size_t e, bool isbf) {
    return isbf ? b2f(((const u16*)p)[e]) : ((const float*)p)[e];
}

// ---------------- dtype probe: 2048 samples (fp32 low-halves fail w.p. ~0.5 each) ----------------
__global__ void probe_dtype(const void* x, float* flag) {
    __shared__ int allok;
    if (threadIdx.x == 0) allok = 1;
    __syncthreads();
    const u16* p = (const u16*)x;
    bool ok = true;
    for (int i = threadIdx.x; i < 2048; i += 256) {
        float v = b2f(p[i]);
        if (!(v == v) || fabsf(v) >= 1000.f) ok = false;
    }
    if (!ok) allok = 0;
    __syncthreads();
    if (threadIdx.x == 0) flag[0] = allok ? 1.f : 0.f;
}

// ---------------- fp32 VALU GEMM (r2 verbatim; dt GEMM only) ----------------
template<int EP>
__global__ __launch_bounds__(256) void gemm_f32(
    const float* __restrict__ A, int lda,
    const void* __restrict__ Bw, size_t bwo, int ldb,
    float* __restrict__ C, int ldc,
    int Kd,
    const void* __restrict__ bias, size_t biaso,
    const float* __restrict__ resid,
    const float* __restrict__ flagp)
{
    const bool isbf = (*flagp > 0.5f);
    __shared__ float As[16][64];
    __shared__ float Bs[16][64];
    const int tid = threadIdx.x;
    const int tx = tid & 15, ty = tid >> 4;
    const int m0 = blockIdx.y << 6, n0 = blockIdx.x << 6;
    const int la_m = tid >> 2, la_k = (tid & 3) << 2;
    const int lb_k = tid >> 4, lb_n = (tid & 15) << 2;
    float acc[4][4] = {};

    for (int k0 = 0; k0 < Kd; k0 += 16) {
        const float4 av = *(const float4*)&A[(size_t)(m0 + la_m) * lda + k0 + la_k];
        const F4 bv = load4(Bw, bwo + (size_t)(k0 + lb_k) * ldb + n0 + lb_n, isbf);
        __syncthreads();
        As[la_k + 0][la_m] = av.x; As[la_k + 1][la_m] = av.y;
        As[la_k + 2][la_m] = av.z; As[la_k + 3][la_m] = av.w;
        Bs[lb_k][lb_n + 0] = bv.x; Bs[lb_k][lb_n + 1] = bv.y;
        Bs[lb_k][lb_n + 2] = bv.z; Bs[lb_k][lb_n + 3] = bv.w;
        __syncthreads();
        #pragma unroll
        for (int k = 0; k < 16; k++) {
            const float4 a = *(const float4*)&As[k][ty << 2];
            const float4 b = *(const float4*)&Bs[k][tx << 2];
            acc[0][0] = fmaf(a.x, b.x, acc[0][0]); acc[0][1] = fmaf(a.x, b.y, acc[0][1]);
            acc[0][2] = fmaf(a.x, b.z, acc[0][2]); acc[0][3] = fmaf(a.x, b.w, acc[0][3]);
            acc[1][0] = fmaf(a.y, b.x, acc[1][0]); acc[1][1] = fmaf(a.y, b.y, acc[1][1]);
            acc[1][2] = fmaf(a.y, b.z, acc[1][2]); acc[1][3] = fmaf(a.y, b.w, acc[1][3]);
            acc[2][0] = fmaf(a.z, b.x, acc[2][0]); acc[2][1] = fmaf(a.z, b.y, acc[2][1]);
            acc[2][2] = fmaf(a.z, b.z, acc[2][2]); acc[2][3] = fmaf(a.z, b.w, acc[2][3]);
            acc[3][0] = fmaf(a.w, b.x, acc[3][0]); acc[3][1] = fmaf(a.w, b.y, acc[3][1]);
            acc[3][2] = fmaf(a.w, b.z, acc[3][2]); acc[3][3] = fmaf(a.w, b.w, acc[3][3]);
        }
    }
    #pragma unroll
    for (int i = 0; i < 4; i++) {
        const int row = m0 + (ty << 2) + i;
        const int col = n0 + (tx << 2);
        float v[4];
        #pragma unroll
        for (int j = 0; j < 4; j++) {
            float t = acc[i][j];
            if (EP == 1) { t += load1(bias, biaso + col + j, isbf);
                           t = (t > 20.f) ? t : log1pf(expf(t)); }
            if (EP == 2) { t += resid[(size_t)row * ldc + col + j]; }
            v[j] = t;
        }
        *(float4*)&C[(size_t)row * ldc + col] = make_float4(v[0], v[1], v[2], v[3]);
    }
}

// ---------------- MFMA GEMM: C(fp32)[M][N] = A(fp32)[M][K] @ B(flag dtype)[K][N] ----------------
// BM = 32*MT, BK=32, 256 threads = 4 waves (2x2); per-wave MT x NT 16x16 frags (16x16x32 MFMA).
// A fp32->bf16 in staging; B dtype-dispatched, transposed to LDS [n][k]. fp32 accumulate.
// EP 0: plain store. EP 2: + resid (in-place safe: each element one thread, read-then-write).
template<int BN, int EP, int MT>
__global__ __launch_bounds__(256) void gemm_mfma(
    const float* __restrict__ A, int lda,
    const void* __restrict__ Bg, size_t bgo, int ldb,   // [K][N] row-major, input dtype
    float* __restrict__ C, int ldc,
    int Kd,
    const float* __restrict__ resid,
    const float* __restrict__ flagp)
{
    const bool isbf = (*flagp > 0.5f);
    constexpr int NT = BN / 32;            // n-frags per wave
    constexpr int BM = 32 * MT;
    constexpr int ASLOTS = BM * 4;         // 8-elem col-groups in A tile
    constexpr int AIT = (ASLOTS + 255) / 256;
    __shared__ u16 sA[BM][40];             // [m][k], +8 pad
    __shared__ u16 sB[BN][40];             // [n][k]
    const int tid = threadIdx.x;
    const int lane = tid & 63;
    const int wid = tid >> 6;
    const int wm = wid >> 1, wn = wid & 1;
    const int m0 = blockIdx.y * BM;
    const int n0 = blockIdx.x * BN;
    const int col16 = lane & 15, quad = lane >> 4;

    f32x4 acc[MT][NT];
    #pragma unroll
    for (int i = 0; i < MT; i++)
        #pragma unroll
        for (int j = 0; j < NT; j++) acc[i][j] = {0.f, 0.f, 0.f, 0.f};

    for (int k0 = 0; k0 < Kd; k0 += 32) {
        // A: BM rows x 32 cols fp32, 8 floats per active slot
        float4 f[AIT][2];
        #pragma unroll
        for (int it = 0; it < AIT; it++) {
            const int slot = tid + it * 256;
            if (slot < ASLOTS) {
                const int ar = slot >> 2, ac = (slot & 3) << 3;
                f[it][0] = *(const float4*)&A[(size_t)(m0 + ar) * lda + k0 + ac];
                f[it][1] = *(const float4*)&A[(size_t)(m0 + ar) * lda + k0 + ac + 4];
            }
        }
        // B: 32 k-rows x BN n-cols, dtype-dispatched, transpose into sB[n][k]
        F4 bv[BN / 32];
        int bn4[BN / 32], bkk[BN / 32];
        #pragma unroll
        for (int it = 0; it < BN / 32; it++) {
            const int slot = tid + it * 256;
            bkk[it] = slot & 31;
            bn4[it] = (slot >> 5) << 2;
            bv[it] = load4(Bg, bgo + (size_t)(k0 + bkk[it]) * ldb + n0 + bn4[it], isbf);
        }
        __syncthreads();
        #pragma unroll
        for (int it = 0; it < AIT; it++) {
            const int slot = tid + it * 256;
            if (slot < ASLOTS) {
                const int ar = slot >> 2, ac = (slot & 3) << 3;
                ushort4 lo = make_ushort4(f2b(f[it][0].x), f2b(f[it][0].y), f2b(f[it][0].z), f2b(f[it][0].w));
                ushort4 hi = make_ushort4(f2b(f[it][1].x), f2b(f[it][1].y), f2b(f[it][1].z), f2b(f[it][1].w));
                *(ushort4*)&sA[ar][ac] = lo;
                *(ushort4*)&sA[ar][ac + 4] = hi;
            }
        }
        #pragma unroll
        for (int it = 0; it < BN / 32; it++) {
            sB[bn4[it] + 0][bkk[it]] = f2b(bv[it].x);
            sB[bn4[it] + 1][bkk[it]] = f2b(bv[it].y);
            sB[bn4[it] + 2][bkk[it]] = f2b(bv[it].z);
            sB[bn4[it] + 3][bkk[it]] = f2b(bv[it].w);
        }
        __syncthreads();
        // fragments: A[m = lane&15][k = quad*8+j], B[n = lane&15][k = quad*8+j]
        bf16x8 af[MT], bfr[NT];
        #pragma unroll
        for (int mi = 0; mi < MT; mi++)
            af[mi] = *(const bf16x8*)&sA[wm * (16 * MT) + mi * 16 + col16][quad * 8];
        #pragma unroll
        for (int ni = 0; ni < NT; ni++)
            bfr[ni] = *(const bf16x8*)&sB[wn * (BN / 2) + ni * 16 + col16][quad * 8];
        #pragma unroll
        for (int mi = 0; mi < MT; mi++)
            #pragma unroll
            for (int ni = 0; ni < NT; ni++)
                acc[mi][ni] = __builtin_amdgcn_mfma_f32_16x16x32_bf16(
                    af[mi], bfr[ni], acc[mi][ni], 0, 0, 0);
    }
    // epilogue: C/D layout col = lane&15, row = quad*4 + reg  [m89/m91 verified]
    #pragma unroll
    for (int mi = 0; mi < MT; mi++) {
        #pragma unroll
        for (int ni = 0; ni < NT; ni++) {
            #pragma unroll
            for (int rr = 0; rr < 4; rr++) {
                const int row = m0 + wm * (16 * MT) + mi * 16 + quad * 4 + rr;
                const int col = n0 + wn * (BN / 2) + ni * 16 + col16;
                float t = acc[mi][ni][rr];
                if (EP == 2) t += resid[(size_t)row * ldc + col];
                C[(size_t)row * ldc + col] = t;
            }
        }
    }
}

// ---------------- depthwise causal conv(4) + bias + SiLU (r2 verbatim) ----------------
__global__ __launch_bounds__(256) void conv_silu(
    const float* __restrict__ xz, const void* __restrict__ cw, size_t cwo,
    const void* __restrict__ cb, size_t cbo, float* __restrict__ xc,
    const float* __restrict__ flagp)
{
    const bool isbf = (*flagp > 0.5f);
    const int idx = blockIdx.x * 256 + threadIdx.x;
    const int d = idx & (DI - 1);
    const int row = idx >> 10;
    const int l = row & (L_ - 1);
    const F4 wv = load4(cw, cwo + (size_t)d * 4, isbf);
    const float* base = xz + (size_t)row * 2048 + d;
    float acc = load1(cb, cbo + d, isbf) + wv.w * base[0];
    if (l >= 1) acc += wv.z * base[-2048];
    if (l >= 2) acc += wv.y * base[-4096];
    if (l >= 3) acc += wv.x * base[-6144];
    xc[idx] = silu_(acc);
}

// ---------------- scan phase 1: per-chunk local scan + sum(dt) summary (CH=16) ----------------
__global__ __launch_bounds__(256) void scan_phase1(
    const float* __restrict__ dtb, const float* __restrict__ xcb,
    const float* __restrict__ dbc, const void* __restrict__ Alog, size_t alo,
    float* __restrict__ Sdt, float* __restrict__ Sbuf,
    const float* __restrict__ flagp)
{
    const bool isbf = (*flagp > 0.5f);
    __shared__ float sB[CH][16];
    const int blk = blockIdx.x;                 // 2 * 128 * 4 = 1024 blocks
    const int dblk = blk & 3;
    const int c = (blk >> 2) & (NC - 1);
    const int b = blk >> 9;
    const int d = dblk * 256 + threadIdx.x;
    const int row0 = b * L_ + c * CH;
    if (threadIdx.x < CH * 4) {                 // stage B-chunk (16 x 16)
        const int l = threadIdx.x >> 2, s4 = (threadIdx.x & 3) << 2;
        *(float4*)&sB[l][s4] = *(const float4*)&dbc[(size_t)(row0 + l) * 64 + 32 + s4];
    }
    __syncthreads();
    float A[DS];
    #pragma unroll
    for (int s = 0; s < DS; s++) A[s] = -expf(load1(Alog, alo + (size_t)d * DS + s, isbf));
    float h[DS];
    #pragma unroll
    for (int s = 0; s < DS; s++) h[s] = 0.f;
    float sdt = 0.f;
    for (int l = 0; l < CH; l++) {
        const int row = row0 + l;
        const float dtv = dtb[(size_t)row * DI + d];
        const float xv  = xcb[(size_t)row * DI + d];
        sdt += dtv;
        const float dtx = dtv * xv;
        #pragma unroll
        for (int s = 0; s < DS; s++) {
            const float dA = expf(dtv * A[s]);
            h[s] = fmaf(dA, h[s], dtx * sB[l][s]);
        }
    }
    const int cb_ = b * NC + c;
    Sdt[(size_t)cb_ * DI + d] = sdt;
    #pragma unroll
    for (int s = 0; s < DS; s++) Sbuf[((size_t)cb_ * DS + s) * DI + d] = h[s];
}

// ---------------- scan phase 2: in-place exclusive scan over chunk summaries ----------------
__global__ __launch_bounds__(256) void scan_phase2(
    const float* __restrict__ Sdt, float* __restrict__ Sbuf,
    const void* __restrict__ Alog, size_t alo,
    const float* __restrict__ flagp)
{
    const bool isbf = (*flagp > 0.5f);
    const int g = blockIdx.x * 256 + threadIdx.x;   // 32768 threads
    const int d = g & (DI - 1);
    const int s = (g >> 10) & (DS - 1);
    const int b = g >> 14;
    const float A = -expf(load1(Alog, alo + (size_t)d * DS + s, isbf));
    float h = 0.f;
    for (int c = 0; c < NC; c++) {
        const int cb_ = b * NC + c;
        const size_t idx = ((size_t)cb_ * DS + s) * DI + d;
        const float tmp = Sbuf[idx];
        Sbuf[idx] = h;                               // exclusive prefix (chunk-initial state)
        const float P = expf(A * Sdt[(size_t)cb_ * DI + d]);
        h = fmaf(P, h, tmp);
    }
}

// ---------------- scan phase 3: replay chunk with true init, fuse y/D/z-gate (CH=16) ----------------
__global__ __launch_bounds__(256) void scan_phase3(
    const float* __restrict__ dtb, float* __restrict__ xcb,
    const float* __restrict__ dbc, const void* __restrict__ Alog, size_t alo,
    const float* __restrict__ H0, const void* __restrict__ Dpv, size_t dpo,
    const float* __restrict__ xz, const float* __restrict__ flagp)
{
    const bool isbf = (*flagp > 0.5f);
    __shared__ float sBC[CH][32];
    const int blk = blockIdx.x;
    const int dblk = blk & 3;
    const int c = (blk >> 2) & (NC - 1);
    const int b = blk >> 9;
    const int d = dblk * 256 + threadIdx.x;
    const int row0 = b * L_ + c * CH;
    if (threadIdx.x < CH * 8) {                 // stage B and C chunk (16 x 32)
        const int l = threadIdx.x >> 3, q = (threadIdx.x & 7) << 2;
        *(float4*)&sBC[l][q] = *(const float4*)&dbc[(size_t)(row0 + l) * 64 + 32 + q];
    }
    __syncthreads();
    float A[DS];
    #pragma unroll
    for (int s = 0; s < DS; s++) A[s] = -expf(load1(Alog, alo + (size_t)d * DS + s, isbf));
    const int cb_ = b * NC + c;
    float h[DS];
    #pragma unroll
    for (int s = 0; s < DS; s++) h[s] = H0[((size_t)cb_ * DS + s) * DI + d];
    const float Dpd = load1(Dpv, dpo + d, isbf);
    for (int l = 0; l < CH; l++) {
        const int row = row0 + l;
        const float dtv = dtb[(size_t)row * DI + d];
        const float xv  = xcb[(size_t)row * DI + d];
        const float dtx = dtv * xv;
        float y = 0.f;
        #pragma unroll
        for (int s = 0; s < DS; s++) {
            const float dA = expf(dtv * A[s]);
            h[s] = fmaf(dA, h[s], dtx * sBC[l][s]);
            y = fmaf(h[s], sBC[l][16 + s], y);
        }
        y = fmaf(xv, Dpd, y);
        const float zv = xz[(size_t)row * 2048 + DI + d];
        y *= silu_(zv);
        xcb[(size_t)row * DI + d] = y;
    }
}

__global__ void cast_in(const void* __restrict__ in, float* __restrict__ out, int n,
                        const float* __restrict__ flagp) {
    const bool isbf = (*flagp > 0.5f);
    const int i = blockIdx.x * 256 + threadIdx.x;
    if (i < n) out[i] = load1(in, (size_t)i, isbf);
}
__global__ void cast_out(const float* __restrict__ in, void* __restrict__ out, int n,
                         const float* __restrict__ flagp) {
    const bool isbf = (*flagp > 0.5f);
    const int i = blockIdx.x * 256 + threadIdx.x;
    if (i < n) {
        if (isbf) ((u16*)out)[i] = f2b(in[i]);
        else      ((float*)out)[i] = in[i];
    }
}

extern "C" void kernel_launch(void* const* d_in, const int* in_sizes, int n_in,
                              void* d_out, int out_size, void* d_ws, size_t ws_size,
                              hipStream_t stream)
{
    const void* x_in  = d_in[0];
    const void* W_in  = d_in[1];
    const void* convw = d_in[2];
    const void* convb = d_in[3];
    const void* W_x   = d_in[4];
    const void* W_dt  = d_in[5];
    const void* b_dt  = d_in[6];
    const void* A_log = d_in[7];
    const void* Dp    = d_in[8];
    const void* W_out = d_in[9];

    float* ws = (float*)d_ws;
    float* flag = ws;                                // 4 floats
    float* xz   = ws + 4;                            // 8M floats
    float* xc   = xz  + (size_t)MROWS * 2048;        // 4M
    float* dbc  = xc  + (size_t)MROWS * DI;          // 256K
    float* dtb  = dbc + (size_t)MROWS * 64;          // 4M
    float* Sdt  = dtb + (size_t)MROWS * DI;          // 256K  (2*128*1024)
    float* Sbuf = Sdt + (size_t)2 * NC * DI;         // 4M    (2*128*16*1024)
    float* xb   = Sbuf + (size_t)2 * NC * DS * DI;   // 2M    -- total ~94.4 MB
    // r2's proven layout was ~93.6 MB; same ballpark.

    probe_dtype<<<1, 256, 0, stream>>>(x_in, flag);
    cast_in<<<(MROWS * DM) / 256, 256, 0, stream>>>(x_in, xb, MROWS * DM, flag);

    for (int i = 0; i < NBLK; i++) {
        // xz = x @ W_in  (4096 x 2048, K=512) -- MFMA, BM=128
        gemm_mfma<128, 0, 4><<<dim3(2048 / 128, MROWS / 128), 256, 0, stream>>>(
            xb, DM, W_in, (size_t)i * DM * 2048, 2048, xz, 2048, DM, nullptr, flag);
        // xc = silu(conv(xi) + cb)
        conv_silu<<<(MROWS * DI) / 256, 256, 0, stream>>>(
            xz, convw, (size_t)i * DI * 4, convb, (size_t)i * DI, xc, flag);
        // dbc = xc @ W_x  (4096 x 64, K=1024) -- MFMA, BM=32 -> 128 blocks
        gemm_mfma<64, 0, 1><<<dim3(1, MROWS / 32), 256, 0, stream>>>(
            xc, DI, W_x, (size_t)i * DI * 64, 64, dbc, 64, DI, nullptr, flag);
        // dt = softplus(dt_raw @ W_dt + b_dt)  (4096 x 1024, K=32) -- fp32 VALU
        gemm_f32<1><<<dim3(DI / 64, MROWS / 64), 256, 0, stream>>>(
            dbc, 64, W_dt, (size_t)i * 32 * DI, DI, dtb, DI, 32, b_dt, (size_t)i * DI, nullptr, flag);
        // selective scan: 128 chunks x 16 steps, in-place exclusive scan in Sbuf
        scan_phase1<<<2 * NC * 4, 256, 0, stream>>>(dtb, xc, dbc, A_log, (size_t)i * DI * DS,
                                                    Sdt, Sbuf, flag);
        scan_phase2<<<128, 256, 0, stream>>>(Sdt, Sbuf, A_log, (size_t)i * DI * DS, flag);
        scan_phase3<<<2 * NC * 4, 256, 0, stream>>>(dtb, xc, dbc, A_log, (size_t)i * DI * DS,
                                                    Sbuf, Dp, (size_t)i * DI, xz, flag);
        // out = y @ W_out + resid  (4096 x 512, K=1024) -- MFMA, in-place residual
        gemm_mfma<128, 2, 4><<<dim3(DM / 128, MROWS / 128), 256, 0, stream>>>(
            xc, DI, W_out, (size_t)i * DI * DM, DM, xb, DM, DI, xb, flag);
    }
    cast_out<<<(MROWS * DM) / 256, 256, 0, stream>>>(xb, d_out, MROWS * DM, flag);
}

// Round 7
// 1102.970 us; speedup vs baseline: 1.6457x; 1.0931x over previous
//
#include <hip/hip_runtime.h>

// MambaEncoder: B=2, L=2048, D_MODEL=512, D_INNER=1024, DT_RANK=32, D_STATE=16, 4 blocks.
// Round 7 (from r6 pass @1206us; GEMM counters: MfmaUtil 2%, VALU 5%, HBM 8% = latency-stalled):
// (1) per-layer weight pre-transpose to bf16 [N][K] -> B staging is coalesced + conflict-free;
// (2) software-pipelined K-loop (register prefetch of next tile overlaps MFMA);
// (3) BM=64 tiles -> 1024/512 blocks for GEMM1/GEMM3 (4/2 blocks per CU).
// Scans (NC=128), conv, probe, dt-GEMM, casts: r6 verbatim (verified).

#define L_    2048
#define DM    512
#define DI    1024
#define DS    16
#define NBLK  4
#define NC    128
#define CH    16
#define MROWS 4096   // B_ * L_

using u16 = unsigned short;
typedef __bf16 bf16x8 __attribute__((ext_vector_type(8)));
typedef float  f32x4  __attribute__((ext_vector_type(4)));

__device__ __forceinline__ float b2f(u16 u) {
    union { unsigned int i; float f; } v; v.i = ((unsigned int)u) << 16; return v.f;
}
__device__ __forceinline__ u16 f2b(float f) {
    union { float f; unsigned int i; } v; v.f = f;
    unsigned int x = v.i;
    return (u16)((x + 0x7FFFu + ((x >> 16) & 1u)) >> 16);
}
__device__ __forceinline__ float silu_(float x) { return x / (1.f + expf(-x)); }

struct F4 { float x, y, z, w; };
__device__ __forceinline__ F4 load4(const void* p, size_t e, bool isbf) {
    F4 r;
    if (isbf) {
        ushort4 v = *(const ushort4*)((const u16*)p + e);
        r.x = b2f(v.x); r.y = b2f(v.y); r.z = b2f(v.z); r.w = b2f(v.w);
    } else {
        float4 v = *(const float4*)((const float*)p + e);
        r.x = v.x; r.y = v.y; r.z = v.z; r.w = v.w;
    }
    return r;
}
__device__ __forceinline__ float load1(const void* p, size_t e, bool isbf) {
    return isbf ? b2f(((const u16*)p)[e]) : ((const float*)p)[e];
}

// ---------------- dtype probe ----------------
__global__ void probe_dtype(const void* x, float* flag) {
    __shared__ int allok;
    if (threadIdx.x == 0) allok = 1;
    __syncthreads();
    const u16* p = (const u16*)x;
    bool ok = true;
    for (int i = threadIdx.x; i < 2048; i += 256) {
        float v = b2f(p[i]);
        if (!(v == v) || fabsf(v) >= 1000.f) ok = false;
    }
    if (!ok) allok = 0;
    __syncthreads();
    if (threadIdx.x == 0) flag[0] = allok ? 1.f : 0.f;
}

// ---------------- weight transpose: src[R][C] (flag dtype) -> dst[C][R] bf16 ----------------
__global__ __launch_bounds__(256) void transpose_wb(
    const void* __restrict__ src, size_t so, int R, int C,
    u16* __restrict__ dst, const float* __restrict__ flagp)
{
    const bool isbf = (*flagp > 0.5f);
    __shared__ u16 t[32][33];
    const int c0 = blockIdx.x * 32, r0 = blockIdx.y * 32;
    const int tx = threadIdx.x & 31, ty = threadIdx.x >> 5;   // 32 x 8
    #pragma unroll
    for (int i = 0; i < 32; i += 8)
        t[ty + i][tx] = f2b(load1(src, so + (size_t)(r0 + ty + i) * C + c0 + tx, isbf));
    __syncthreads();
    #pragma unroll
    for (int i = 0; i < 32; i += 8)
        dst[(size_t)(c0 + ty + i) * R + r0 + tx] = t[tx][ty + i];
}

// ---------------- fp32 VALU GEMM (dt GEMM only; r2 verbatim) ----------------
template<int EP>
__global__ __launch_bounds__(256) void gemm_f32(
    const float* __restrict__ A, int lda,
    const void* __restrict__ Bw, size_t bwo, int ldb,
    float* __restrict__ C, int ldc,
    int Kd,
    const void* __restrict__ bias, size_t biaso,
    const float* __restrict__ resid,
    const float* __restrict__ flagp)
{
    const bool isbf = (*flagp > 0.5f);
    __shared__ float As[16][64];
    __shared__ float Bs[16][64];
    const int tid = threadIdx.x;
    const int tx = tid & 15, ty = tid >> 4;
    const int m0 = blockIdx.y << 6, n0 = blockIdx.x << 6;
    const int la_m = tid >> 2, la_k = (tid & 3) << 2;
    const int lb_k = tid >> 4, lb_n = (tid & 15) << 2;
    float acc[4][4] = {};

    for (int k0 = 0; k0 < Kd; k0 += 16) {
        const float4 av = *(const float4*)&A[(size_t)(m0 + la_m) * lda + k0 + la_k];
        const F4 bv = load4(Bw, bwo + (size_t)(k0 + lb_k) * ldb + n0 + lb_n, isbf);
        __syncthreads();
        As[la_k + 0][la_m] = av.x; As[la_k + 1][la_m] = av.y;
        As[la_k + 2][la_m] = av.z; As[la_k + 3][la_m] = av.w;
        Bs[lb_k][lb_n + 0] = bv.x; Bs[lb_k][lb_n + 1] = bv.y;
        Bs[lb_k][lb_n + 2] = bv.z; Bs[lb_k][lb_n + 3] = bv.w;
        __syncthreads();
        #pragma unroll
        for (int k = 0; k < 16; k++) {
            const float4 a = *(const float4*)&As[k][ty << 2];
            const float4 b = *(const float4*)&Bs[k][tx << 2];
            acc[0][0] = fmaf(a.x, b.x, acc[0][0]); acc[0][1] = fmaf(a.x, b.y, acc[0][1]);
            acc[0][2] = fmaf(a.x, b.z, acc[0][2]); acc[0][3] = fmaf(a.x, b.w, acc[0][3]);
            acc[1][0] = fmaf(a.y, b.x, acc[1][0]); acc[1][1] = fmaf(a.y, b.y, acc[1][1]);
            acc[1][2] = fmaf(a.y, b.z, acc[1][2]); acc[1][3] = fmaf(a.y, b.w, acc[1][3]);
            acc[2][0] = fmaf(a.z, b.x, acc[2][0]); acc[2][1] = fmaf(a.z, b.y, acc[2][1]);
            acc[2][2] = fmaf(a.z, b.z, acc[2][2]); acc[2][3] = fmaf(a.z, b.w, acc[2][3]);
            acc[3][0] = fmaf(a.w, b.x, acc[3][0]); acc[3][1] = fmaf(a.w, b.y, acc[3][1]);
            acc[3][2] = fmaf(a.w, b.z, acc[3][2]); acc[3][3] = fmaf(a.w, b.w, acc[3][3]);
        }
    }
    #pragma unroll
    for (int i = 0; i < 4; i++) {
        const int row = m0 + (ty << 2) + i;
        const int col = n0 + (tx << 2);
        float v[4];
        #pragma unroll
        for (int j = 0; j < 4; j++) {
            float t = acc[i][j];
            if (EP == 1) { t += load1(bias, biaso + col + j, isbf);
                           t = (t > 20.f) ? t : log1pf(expf(t)); }
            if (EP == 2) { t += resid[(size_t)row * ldc + col + j]; }
            v[j] = t;
        }
        *(float4*)&C[(size_t)row * ldc + col] = make_float4(v[0], v[1], v[2], v[3]);
    }
}

// ---------------- MFMA GEMM: C(fp32)[M][N] = A(fp32)[M][K] @ BT(bf16,[N][K])^T ----------------
// BM=32*MT, BK=32, 256 threads = 4 waves (2x2 wm x wn). Software-pipelined: registers hold
// tile k+1 while MFMA consumes tile k from LDS. A fp32->bf16 in staging; BT loads are 16B
// contiguous-k, identity LDS store (no transpose, conflict-free). fp32 accumulate.
// EP 0: plain store. EP 2: + resid (in-place safe).
template<int BN, int EP, int MT>
__global__ __launch_bounds__(256) void gemm_mfma(
    const float* __restrict__ A, int lda,
    const u16* __restrict__ BT,          // [N][K] bf16, row stride Kd
    float* __restrict__ C, int ldc,
    int Kd,
    const float* __restrict__ resid)
{
    constexpr int NT = BN / 32;            // n-frags per wave
    constexpr int BM = 32 * MT;
    constexpr int ASL = BM * 4;            // 8-float slots in A tile
    constexpr int AIT = (ASL + 255) / 256;
    constexpr int BSL = BN * 4;            // 8-u16 slots in B tile
    constexpr int BIT = (BSL + 255) / 256;
    __shared__ u16 sA[BM][40];             // [m][k], +8 pad
    __shared__ u16 sB[BN][40];             // [n][k]
    const int tid = threadIdx.x;
    const int lane = tid & 63;
    const int wid = tid >> 6;
    const int wm = wid >> 1, wn = wid & 1;
    const int m0 = blockIdx.y * BM;
    const int n0 = blockIdx.x * BN;
    const int col16 = lane & 15, quad = lane >> 4;

    f32x4 acc[MT][NT];
    #pragma unroll
    for (int i = 0; i < MT; i++)
        #pragma unroll
        for (int j = 0; j < NT; j++) acc[i][j] = {0.f, 0.f, 0.f, 0.f};

    float4 fa[AIT][2];
    int4   fb[BIT];
    // prologue: load tile k0=0 into registers
    #pragma unroll
    for (int it = 0; it < AIT; it++) {
        const int slot = tid + it * 256;
        if (slot < ASL) {
            const int ar = slot >> 2, ac = (slot & 3) << 3;
            fa[it][0] = *(const float4*)&A[(size_t)(m0 + ar) * lda + ac];
            fa[it][1] = *(const float4*)&A[(size_t)(m0 + ar) * lda + ac + 4];
        }
    }
    #pragma unroll
    for (int it = 0; it < BIT; it++) {
        const int slot = tid + it * 256;
        if (slot < BSL) {
            const int br = slot >> 2, bc = (slot & 3) << 3;
            fb[it] = *(const int4*)&BT[(size_t)(n0 + br) * Kd + bc];
        }
    }

    for (int k0 = 0;;) {
        __syncthreads();                       // LDS free (prev compute done)
        #pragma unroll
        for (int it = 0; it < AIT; it++) {
            const int slot = tid + it * 256;
            if (slot < ASL) {
                const int ar = slot >> 2, ac = (slot & 3) << 3;
                ushort4 lo = make_ushort4(f2b(fa[it][0].x), f2b(fa[it][0].y),
                                          f2b(fa[it][0].z), f2b(fa[it][0].w));
                ushort4 hi = make_ushort4(f2b(fa[it][1].x), f2b(fa[it][1].y),
                                          f2b(fa[it][1].z), f2b(fa[it][1].w));
                *(ushort4*)&sA[ar][ac] = lo;
                *(ushort4*)&sA[ar][ac + 4] = hi;
            }
        }
        #pragma unroll
        for (int it = 0; it < BIT; it++) {
            const int slot = tid + it * 256;
            if (slot < BSL) {
                const int br = slot >> 2, bc = (slot & 3) << 3;
                *(int4*)&sB[br][bc] = fb[it];
            }
        }
        __syncthreads();
        k0 += 32;
        const bool more = (k0 < Kd);
        if (more) {                            // prefetch next tile; overlaps MFMA below
            #pragma unroll
            for (int it = 0; it < AIT; it++) {
                const int slot = tid + it * 256;
                if (slot < ASL) {
                    const int ar = slot >> 2, ac = (slot & 3) << 3;
                    fa[it][0] = *(const float4*)&A[(size_t)(m0 + ar) * lda + k0 + ac];
                    fa[it][1] = *(const float4*)&A[(size_t)(m0 + ar) * lda + k0 + ac + 4];
                }
            }
            #pragma unroll
            for (int it = 0; it < BIT; it++) {
                const int slot = tid + it * 256;
                if (slot < BSL) {
                    const int br = slot >> 2, bc = (slot & 3) << 3;
                    fb[it] = *(const int4*)&BT[(size_t)(n0 + br) * Kd + k0 + bc];
                }
            }
        }
        // fragments: A[m = lane&15][k = quad*8+j], B[n = lane&15][k = quad*8+j]
        bf16x8 af[MT], bfr[NT];
        #pragma unroll
        for (int mi = 0; mi < MT; mi++)
            af[mi] = *(const bf16x8*)&sA[wm * (16 * MT) + mi * 16 + col16][quad * 8];
        #pragma unroll
        for (int ni = 0; ni < NT; ni++)
            bfr[ni] = *(const bf16x8*)&sB[wn * (BN / 2) + ni * 16 + col16][quad * 8];
        #pragma unroll
        for (int mi = 0; mi < MT; mi++)
            #pragma unroll
            for (int ni = 0; ni < NT; ni++)
                acc[mi][ni] = __builtin_amdgcn_mfma_f32_16x16x32_bf16(
                    af[mi], bfr[ni], acc[mi][ni], 0, 0, 0);
        if (!more) break;
    }
    // epilogue: C/D layout col = lane&15, row = quad*4 + reg
    #pragma unroll
    for (int mi = 0; mi < MT; mi++) {
        #pragma unroll
        for (int ni = 0; ni < NT; ni++) {
            #pragma unroll
            for (int rr = 0; rr < 4; rr++) {
                const int row = m0 + wm * (16 * MT) + mi * 16 + quad * 4 + rr;
                const int col = n0 + wn * (BN / 2) + ni * 16 + col16;
                float t = acc[mi][ni][rr];
                if (EP == 2) t += resid[(size_t)row * ldc + col];
                C[(size_t)row * ldc + col] = t;
            }
        }
    }
}

// ---------------- depthwise causal conv(4) + bias + SiLU (r2 verbatim) ----------------
__global__ __launch_bounds__(256) void conv_silu(
    const float* __restrict__ xz, const void* __restrict__ cw, size_t cwo,
    const void* __restrict__ cb, size_t cbo, float* __restrict__ xc,
    const float* __restrict__ flagp)
{
    const bool isbf = (*flagp > 0.5f);
    const int idx = blockIdx.x * 256 + threadIdx.x;
    const int d = idx & (DI - 1);
    const int row = idx >> 10;
    const int l = row & (L_ - 1);
    const F4 wv = load4(cw, cwo + (size_t)d * 4, isbf);
    const float* base = xz + (size_t)row * 2048 + d;
    float acc = load1(cb, cbo + d, isbf) + wv.w * base[0];
    if (l >= 1) acc += wv.z * base[-2048];
    if (l >= 2) acc += wv.y * base[-4096];
    if (l >= 3) acc += wv.x * base[-6144];
    xc[idx] = silu_(acc);
}

// ---------------- scan phase 1 (CH=16; r6 verbatim) ----------------
__global__ __launch_bounds__(256) void scan_phase1(
    const float* __restrict__ dtb, const float* __restrict__ xcb,
    const float* __restrict__ dbc, const void* __restrict__ Alog, size_t alo,
    float* __restrict__ Sdt, float* __restrict__ Sbuf,
    const float* __restrict__ flagp)
{
    const bool isbf = (*flagp > 0.5f);
    __shared__ float sB[CH][16];
    const int blk = blockIdx.x;
    const int dblk = blk & 3;
    const int c = (blk >> 2) & (NC - 1);
    const int b = blk >> 9;
    const int d = dblk * 256 + threadIdx.x;
    const int row0 = b * L_ + c * CH;
    if (threadIdx.x < CH * 4) {
        const int l = threadIdx.x >> 2, s4 = (threadIdx.x & 3) << 2;
        *(float4*)&sB[l][s4] = *(const float4*)&dbc[(size_t)(row0 + l) * 64 + 32 + s4];
    }
    __syncthreads();
    float A[DS];
    #pragma unroll
    for (int s = 0; s < DS; s++) A[s] = -expf(load1(Alog, alo + (size_t)d * DS + s, isbf));
    float h[DS];
    #pragma unroll
    for (int s = 0; s < DS; s++) h[s] = 0.f;
    float sdt = 0.f;
    for (int l = 0; l < CH; l++) {
        const int row = row0 + l;
        const float dtv = dtb[(size_t)row * DI + d];
        const float xv  = xcb[(size_t)row * DI + d];
        sdt += dtv;
        const float dtx = dtv * xv;
        #pragma unroll
        for (int s = 0; s < DS; s++) {
            const float dA = expf(dtv * A[s]);
            h[s] = fmaf(dA, h[s], dtx * sB[l][s]);
        }
    }
    const int cb_ = b * NC + c;
    Sdt[(size_t)cb_ * DI + d] = sdt;
    #pragma unroll
    for (int s = 0; s < DS; s++) Sbuf[((size_t)cb_ * DS + s) * DI + d] = h[s];
}

// ---------------- scan phase 2 (in-place exclusive; r6 verbatim) ----------------
__global__ __launch_bounds__(256) void scan_phase2(
    const float* __restrict__ Sdt, float* __restrict__ Sbuf,
    const void* __restrict__ Alog, size_t alo,
    const float* __restrict__ flagp)
{
    const bool isbf = (*flagp > 0.5f);
    const int g = blockIdx.x * 256 + threadIdx.x;
    const int d = g & (DI - 1);
    const int s = (g >> 10) & (DS - 1);
    const int b = g >> 14;
    const float A = -expf(load1(Alog, alo + (size_t)d * DS + s, isbf));
    float h = 0.f;
    for (int c = 0; c < NC; c++) {
        const int cb_ = b * NC + c;
        const size_t idx = ((size_t)cb_ * DS + s) * DI + d;
        const float tmp = Sbuf[idx];
        Sbuf[idx] = h;
        const float P = expf(A * Sdt[(size_t)cb_ * DI + d]);
        h = fmaf(P, h, tmp);
    }
}

// ---------------- scan phase 3 (CH=16; r6 verbatim) ----------------
__global__ __launch_bounds__(256) void scan_phase3(
    const float* __restrict__ dtb, float* __restrict__ xcb,
    const float* __restrict__ dbc, const void* __restrict__ Alog, size_t alo,
    const float* __restrict__ H0, const void* __restrict__ Dpv, size_t dpo,
    const float* __restrict__ xz, const float* __restrict__ flagp)
{
    const bool isbf = (*flagp > 0.5f);
    __shared__ float sBC[CH][32];
    const int blk = blockIdx.x;
    const int dblk = blk & 3;
    const int c = (blk >> 2) & (NC - 1);
    const int b = blk >> 9;
    const int d = dblk * 256 + threadIdx.x;
    const int row0 = b * L_ + c * CH;
    if (threadIdx.x < CH * 8) {
        const int l = threadIdx.x >> 3, q = (threadIdx.x & 7) << 2;
        *(float4*)&sBC[l][q] = *(const float4*)&dbc[(size_t)(row0 + l) * 64 + 32 + q];
    }
    __syncthreads();
    float A[DS];
    #pragma unroll
    for (int s = 0; s < DS; s++) A[s] = -expf(load1(Alog, alo + (size_t)d * DS + s, isbf));
    const int cb_ = b * NC + c;
    float h[DS];
    #pragma unroll
    for (int s = 0; s < DS; s++) h[s] = H0[((size_t)cb_ * DS + s) * DI + d];
    const float Dpd = load1(Dpv, dpo + d, isbf);
    for (int l = 0; l < CH; l++) {
        const int row = row0 + l;
        const float dtv = dtb[(size_t)row * DI + d];
        const float xv  = xcb[(size_t)row * DI + d];
        const float dtx = dtv * xv;
        float y = 0.f;
        #pragma unroll
        for (int s = 0; s < DS; s++) {
            const float dA = expf(dtv * A[s]);
            h[s] = fmaf(dA, h[s], dtx * sBC[l][s]);
            y = fmaf(h[s], sBC[l][16 + s], y);
        }
        y = fmaf(xv, Dpd, y);
        const float zv = xz[(size_t)row * 2048 + DI + d];
        y *= silu_(zv);
        xcb[(size_t)row * DI + d] = y;
    }
}

__global__ void cast_in(const void* __restrict__ in, float* __restrict__ out, int n,
                        const float* __restrict__ flagp) {
    const bool isbf = (*flagp > 0.5f);
    const int i = blockIdx.x * 256 + threadIdx.x;
    if (i < n) out[i] = load1(in, (size_t)i, isbf);
}
__global__ void cast_out(const float* __restrict__ in, void* __restrict__ out, int n,
                         const float* __restrict__ flagp) {
    const bool isbf = (*flagp > 0.5f);
    const int i = blockIdx.x * 256 + threadIdx.x;
    if (i < n) {
        if (isbf) ((u16*)out)[i] = f2b(in[i]);
        else      ((float*)out)[i] = in[i];
    }
}

extern "C" void kernel_launch(void* const* d_in, const int* in_sizes, int n_in,
                              void* d_out, int out_size, void* d_ws, size_t ws_size,
                              hipStream_t stream)
{
    const void* x_in  = d_in[0];
    const void* W_in  = d_in[1];
    const void* convw = d_in[2];
    const void* convb = d_in[3];
    const void* W_x   = d_in[4];
    const void* W_dt  = d_in[5];
    const void* b_dt  = d_in[6];
    const void* A_log = d_in[7];
    const void* Dp    = d_in[8];
    const void* W_out = d_in[9];

    float* ws = (float*)d_ws;
    float* flag = ws;                                // 4 floats
    float* xz   = ws + 4;                            // 8M floats
    float* xc   = xz  + (size_t)MROWS * 2048;        // 4M
    float* dbc  = xc  + (size_t)MROWS * DI;          // 256K
    float* dtb  = dbc + (size_t)MROWS * 64;          // 4M
    float* Sdt  = dtb + (size_t)MROWS * DI;          // 256K
    float* Sbuf = Sdt + (size_t)2 * NC * DI;         // 4M
    float* xb   = Sbuf + (size_t)2 * NC * DS * DI;   // 2M
    u16* WinT  = (u16*)(xb + (size_t)MROWS * DM);    // 2048*512 u16 (per-layer)
    u16* WxT   = WinT + (size_t)2048 * DM;           // 64*1024
    u16* WoutT = WxT + (size_t)64 * DI;              // 512*1024  -- total ~93.3 MB

    probe_dtype<<<1, 256, 0, stream>>>(x_in, flag);
    cast_in<<<(MROWS * DM) / 256, 256, 0, stream>>>(x_in, xb, MROWS * DM, flag);

    for (int i = 0; i < NBLK; i++) {
        // per-layer weight transposes: [K][N] -> bf16 [N][K]
        transpose_wb<<<dim3(2048 / 32, DM / 32), 256, 0, stream>>>(
            W_in, (size_t)i * DM * 2048, DM, 2048, WinT, flag);
        transpose_wb<<<dim3(64 / 32, DI / 32), 256, 0, stream>>>(
            W_x, (size_t)i * DI * 64, DI, 64, WxT, flag);
        transpose_wb<<<dim3(DM / 32, DI / 32), 256, 0, stream>>>(
            W_out, (size_t)i * DI * DM, DI, DM, WoutT, flag);
        // xz = x @ W_in  (4096 x 2048, K=512) -- MFMA, BM=64/BN=128 -> 1024 blocks
        gemm_mfma<128, 0, 2><<<dim3(2048 / 128, MROWS / 64), 256, 0, stream>>>(
            xb, DM, WinT, xz, 2048, DM, nullptr);
        // xc = silu(conv(xi) + cb)
        conv_silu<<<(MROWS * DI) / 256, 256, 0, stream>>>(
            xz, convw, (size_t)i * DI * 4, convb, (size_t)i * DI, xc, flag);
        // dbc = xc @ W_x  (4096 x 64, K=1024) -- MFMA, BM=32/BN=64 -> 128 blocks
        gemm_mfma<64, 0, 1><<<dim3(1, MROWS / 32), 256, 0, stream>>>(
            xc, DI, WxT, dbc, 64, DI, nullptr);
        // dt = softplus(dt_raw @ W_dt + b_dt)  (4096 x 1024, K=32) -- fp32 VALU
        gemm_f32<1><<<dim3(DI / 64, MROWS / 64), 256, 0, stream>>>(
            dbc, 64, W_dt, (size_t)i * 32 * DI, DI, dtb, DI, 32, b_dt, (size_t)i * DI, nullptr, flag);
        // selective scan: 128 chunks x 16 steps
        scan_phase1<<<2 * NC * 4, 256, 0, stream>>>(dtb, xc, dbc, A_log, (size_t)i * DI * DS,
                                                    Sdt, Sbuf, flag);
        scan_phase2<<<128, 256, 0, stream>>>(Sdt, Sbuf, A_log, (size_t)i * DI * DS, flag);
        scan_phase3<<<2 * NC * 4, 256, 0, stream>>>(dtb, xc, dbc, A_log, (size_t)i * DI * DS,
                                                    Sbuf, Dp, (size_t)i * DI, xz, flag);
        // out = y @ W_out + resid  (4096 x 512, K=1024) -- MFMA, BM=64/BN=64 -> 512 blocks
        gemm_mfma<64, 2, 2><<<dim3(DM / 64, MROWS / 64), 256, 0, stream>>>(
            xc, DI, WoutT, xb, DM, DI, xb);
    }
    cast_out<<<(MROWS * DM) / 256, 256, 0, stream>>>(xb, d_out, MROWS * DM, flag);
}

// Round 8
// 992.912 us; speedup vs baseline: 1.8281x; 1.1108x over previous
//
#include <hip/hip_runtime.h>

// MambaEncoder: B=2, L=2048, D_MODEL=512, D_INNER=1024, DT_RANK=32, D_STATE=16, 4 blocks.
// Round 8 (from r7 pass @1103us; GEMM: HBM 25%, 2.4x write amplification, MfmaUtil 5%):
// bf16 activations end-to-end. gemm_bf: A bf16 [M][K] + BT bf16 [N][K], int4 staging (no
// VALU convert), register-prefetch pipeline, 128x128 tile for GEMM1. xz/xc/xb_bf/y all bf16;
// residual stream + dbc/dtb/Sbuf stay fp32. Weight transposes batched over 4 layers.

#define L_    2048
#define DM    512
#define DI    1024
#define DS    16
#define NBLK  4
#define NC    128
#define CH    16
#define MROWS 4096   // B_ * L_

using u16 = unsigned short;
typedef __bf16 bf16x8 __attribute__((ext_vector_type(8)));
typedef float  f32x4  __attribute__((ext_vector_type(4)));

__device__ __forceinline__ float b2f(u16 u) {
    union { unsigned int i; float f; } v; v.i = ((unsigned int)u) << 16; return v.f;
}
__device__ __forceinline__ u16 f2b(float f) {
    union { float f; unsigned int i; } v; v.f = f;
    unsigned int x = v.i;
    return (u16)((x + 0x7FFFu + ((x >> 16) & 1u)) >> 16);
}
__device__ __forceinline__ float silu_(float x) { return x / (1.f + expf(-x)); }

struct F4 { float x, y, z, w; };
__device__ __forceinline__ F4 load4(const void* p, size_t e, bool isbf) {
    F4 r;
    if (isbf) {
        ushort4 v = *(const ushort4*)((const u16*)p + e);
        r.x = b2f(v.x); r.y = b2f(v.y); r.z = b2f(v.z); r.w = b2f(v.w);
    } else {
        float4 v = *(const float4*)((const float*)p + e);
        r.x = v.x; r.y = v.y; r.z = v.z; r.w = v.w;
    }
    return r;
}
__device__ __forceinline__ float load1(const void* p, size_t e, bool isbf) {
    return isbf ? b2f(((const u16*)p)[e]) : ((const float*)p)[e];
}

// ---------------- dtype probe ----------------
__global__ void probe_dtype(const void* x, float* flag) {
    __shared__ int allok;
    if (threadIdx.x == 0) allok = 1;
    __syncthreads();
    const u16* p = (const u16*)x;
    bool ok = true;
    for (int i = threadIdx.x; i < 2048; i += 256) {
        float v = b2f(p[i]);
        if (!(v == v) || fabsf(v) >= 1000.f) ok = false;
    }
    if (!ok) allok = 0;
    __syncthreads();
    if (threadIdx.x == 0) flag[0] = allok ? 1.f : 0.f;
}

// ---------------- weight transpose: src[z][R][C] (flag dtype) -> dst[z][C][R] bf16 ----------------
__global__ __launch_bounds__(256) void transpose_wb(
    const void* __restrict__ src, int R, int C,
    u16* __restrict__ dst, const float* __restrict__ flagp)
{
    const bool isbf = (*flagp > 0.5f);
    __shared__ u16 t[32][33];
    const size_t mo = (size_t)blockIdx.z * R * C;
    const int c0 = blockIdx.x * 32, r0 = blockIdx.y * 32;
    const int tx = threadIdx.x & 31, ty = threadIdx.x >> 5;   // 32 x 8
    #pragma unroll
    for (int i = 0; i < 32; i += 8)
        t[ty + i][tx] = f2b(load1(src, mo + (size_t)(r0 + ty + i) * C + c0 + tx, isbf));
    __syncthreads();
    #pragma unroll
    for (int i = 0; i < 32; i += 8)
        dst[mo + (size_t)(c0 + ty + i) * R + r0 + tx] = t[tx][ty + i];
}

// ---------------- fp32 VALU GEMM (dt GEMM only; verified) ----------------
template<int EP>
__global__ __launch_bounds__(256) void gemm_f32(
    const float* __restrict__ A, int lda,
    const void* __restrict__ Bw, size_t bwo, int ldb,
    float* __restrict__ C, int ldc,
    int Kd,
    const void* __restrict__ bias, size_t biaso,
    const float* __restrict__ resid,
    const float* __restrict__ flagp)
{
    const bool isbf = (*flagp > 0.5f);
    __shared__ float As[16][64];
    __shared__ float Bs[16][64];
    const int tid = threadIdx.x;
    const int tx = tid & 15, ty = tid >> 4;
    const int m0 = blockIdx.y << 6, n0 = blockIdx.x << 6;
    const int la_m = tid >> 2, la_k = (tid & 3) << 2;
    const int lb_k = tid >> 4, lb_n = (tid & 15) << 2;
    float acc[4][4] = {};

    for (int k0 = 0; k0 < Kd; k0 += 16) {
        const float4 av = *(const float4*)&A[(size_t)(m0 + la_m) * lda + k0 + la_k];
        const F4 bv = load4(Bw, bwo + (size_t)(k0 + lb_k) * ldb + n0 + lb_n, isbf);
        __syncthreads();
        As[la_k + 0][la_m] = av.x; As[la_k + 1][la_m] = av.y;
        As[la_k + 2][la_m] = av.z; As[la_k + 3][la_m] = av.w;
        Bs[lb_k][lb_n + 0] = bv.x; Bs[lb_k][lb_n + 1] = bv.y;
        Bs[lb_k][lb_n + 2] = bv.z; Bs[lb_k][lb_n + 3] = bv.w;
        __syncthreads();
        #pragma unroll
        for (int k = 0; k < 16; k++) {
            const float4 a = *(const float4*)&As[k][ty << 2];
            const float4 b = *(const float4*)&Bs[k][tx << 2];
            acc[0][0] = fmaf(a.x, b.x, acc[0][0]); acc[0][1] = fmaf(a.x, b.y, acc[0][1]);
            acc[0][2] = fmaf(a.x, b.z, acc[0][2]); acc[0][3] = fmaf(a.x, b.w, acc[0][3]);
            acc[1][0] = fmaf(a.y, b.x, acc[1][0]); acc[1][1] = fmaf(a.y, b.y, acc[1][1]);
            acc[1][2] = fmaf(a.y, b.z, acc[1][2]); acc[1][3] = fmaf(a.y, b.w, acc[1][3]);
            acc[2][0] = fmaf(a.z, b.x, acc[2][0]); acc[2][1] = fmaf(a.z, b.y, acc[2][1]);
            acc[2][2] = fmaf(a.z, b.z, acc[2][2]); acc[2][3] = fmaf(a.z, b.w, acc[2][3]);
            acc[3][0] = fmaf(a.w, b.x, acc[3][0]); acc[3][1] = fmaf(a.w, b.y, acc[3][1]);
            acc[3][2] = fmaf(a.w, b.z, acc[3][2]); acc[3][3] = fmaf(a.w, b.w, acc[3][3]);
        }
    }
    #pragma unroll
    for (int i = 0; i < 4; i++) {
        const int row = m0 + (ty << 2) + i;
        const int col = n0 + (tx << 2);
        float v[4];
        #pragma unroll
        for (int j = 0; j < 4; j++) {
            float t = acc[i][j];
            if (EP == 1) { t += load1(bias, biaso + col + j, isbf);
                           t = (t > 20.f) ? t : log1pf(expf(t)); }
            if (EP == 2) { t += resid[(size_t)row * ldc + col + j]; }
            v[j] = t;
        }
        *(float4*)&C[(size_t)row * ldc + col] = make_float4(v[0], v[1], v[2], v[3]);
    }
}

// ---------------- MFMA GEMM, all-bf16 path: C = A(bf16,[M][K]) @ BT(bf16,[N][K])^T ----------------
// BM=32*MT, BK=32, 256 threads = 4 waves (2x2). Register-prefetch pipeline (r7-proven).
// Staging is pure int4 loads + int4 LDS stores (no convert). fp32 accumulate.
// OM 0: store bf16 Cb. OM 1: store fp32 Cf. OM 2: +resid fp32, dual-store Cf and Cb.
template<int BN, int MT, int OM>
__global__ __launch_bounds__(256) void gemm_bf(
    const u16* __restrict__ A, int lda,
    const u16* __restrict__ BT, int Kd,
    u16* __restrict__ Cb, float* __restrict__ Cf, int ldc,
    const float* __restrict__ resid)
{
    constexpr int NT = BN / 32;
    constexpr int BM = 32 * MT;
    constexpr int ASL = BM * 4;            // 16B slots in A tile (BM x 32 bf16)
    constexpr int AIT = (ASL + 255) / 256;
    constexpr int BSL = BN * 4;
    constexpr int BIT = (BSL + 255) / 256;
    __shared__ u16 sA[BM][40];             // [m][k], +8 pad
    __shared__ u16 sB[BN][40];             // [n][k]
    const int tid = threadIdx.x;
    const int lane = tid & 63;
    const int wid = tid >> 6;
    const int wm = wid >> 1, wn = wid & 1;
    const int m0 = blockIdx.y * BM;
    const int n0 = blockIdx.x * BN;
    const int col16 = lane & 15, quad = lane >> 4;

    f32x4 acc[MT][NT];
    #pragma unroll
    for (int i = 0; i < MT; i++)
        #pragma unroll
        for (int j = 0; j < NT; j++) acc[i][j] = {0.f, 0.f, 0.f, 0.f};

    int4 fa[AIT], fb[BIT];
    #pragma unroll
    for (int it = 0; it < AIT; it++) {
        const int slot = tid + it * 256;
        if (slot < ASL) {
            const int ar = slot >> 2, ac = (slot & 3) << 3;
            fa[it] = *(const int4*)&A[(size_t)(m0 + ar) * lda + ac];
        }
    }
    #pragma unroll
    for (int it = 0; it < BIT; it++) {
        const int slot = tid + it * 256;
        if (slot < BSL) {
            const int br = slot >> 2, bc = (slot & 3) << 3;
            fb[it] = *(const int4*)&BT[(size_t)(n0 + br) * Kd + bc];
        }
    }

    for (int k0 = 0;;) {
        __syncthreads();
        #pragma unroll
        for (int it = 0; it < AIT; it++) {
            const int slot = tid + it * 256;
            if (slot < ASL) {
                const int ar = slot >> 2, ac = (slot & 3) << 3;
                *(int4*)&sA[ar][ac] = fa[it];
            }
        }
        #pragma unroll
        for (int it = 0; it < BIT; it++) {
            const int slot = tid + it * 256;
            if (slot < BSL) {
                const int br = slot >> 2, bc = (slot & 3) << 3;
                *(int4*)&sB[br][bc] = fb[it];
            }
        }
        __syncthreads();
        k0 += 32;
        const bool more = (k0 < Kd);
        if (more) {                          // prefetch next tile; overlaps MFMA below
            #pragma unroll
            for (int it = 0; it < AIT; it++) {
                const int slot = tid + it * 256;
                if (slot < ASL) {
                    const int ar = slot >> 2, ac = (slot & 3) << 3;
                    fa[it] = *(const int4*)&A[(size_t)(m0 + ar) * lda + k0 + ac];
                }
            }
            #pragma unroll
            for (int it = 0; it < BIT; it++) {
                const int slot = tid + it * 256;
                if (slot < BSL) {
                    const int br = slot >> 2, bc = (slot & 3) << 3;
                    fb[it] = *(const int4*)&BT[(size_t)(n0 + br) * Kd + k0 + bc];
                }
            }
        }
        bf16x8 af[MT], bfr[NT];
        #pragma unroll
        for (int mi = 0; mi < MT; mi++)
            af[mi] = *(const bf16x8*)&sA[wm * (16 * MT) + mi * 16 + col16][quad * 8];
        #pragma unroll
        for (int ni = 0; ni < NT; ni++)
            bfr[ni] = *(const bf16x8*)&sB[wn * (BN / 2) + ni * 16 + col16][quad * 8];
        #pragma unroll
        for (int mi = 0; mi < MT; mi++)
            #pragma unroll
            for (int ni = 0; ni < NT; ni++)
                acc[mi][ni] = __builtin_amdgcn_mfma_f32_16x16x32_bf16(
                    af[mi], bfr[ni], acc[mi][ni], 0, 0, 0);
        if (!more) break;
    }
    // epilogue: C/D layout col = lane&15, row = quad*4 + reg
    #pragma unroll
    for (int mi = 0; mi < MT; mi++) {
        #pragma unroll
        for (int ni = 0; ni < NT; ni++) {
            #pragma unroll
            for (int rr = 0; rr < 4; rr++) {
                const int row = m0 + wm * (16 * MT) + mi * 16 + quad * 4 + rr;
                const int col = n0 + wn * (BN / 2) + ni * 16 + col16;
                float t = acc[mi][ni][rr];
                if (OM == 2) t += resid[(size_t)row * ldc + col];
                if (OM == 0 || OM == 2) Cb[(size_t)row * ldc + col] = f2b(t);
                if (OM == 1 || OM == 2) Cf[(size_t)row * ldc + col] = t;
            }
        }
    }
}

// ---------------- depthwise causal conv(4) + bias + SiLU (bf16 in/out) ----------------
__global__ __launch_bounds__(256) void conv_silu(
    const u16* __restrict__ xz, const void* __restrict__ cw, size_t cwo,
    const void* __restrict__ cb, size_t cbo, u16* __restrict__ xc,
    const float* __restrict__ flagp)
{
    const bool isbf = (*flagp > 0.5f);
    const int idx = blockIdx.x * 256 + threadIdx.x;
    const int d = idx & (DI - 1);
    const int row = idx >> 10;
    const int l = row & (L_ - 1);
    const F4 wv = load4(cw, cwo + (size_t)d * 4, isbf);
    const u16* base = xz + (size_t)row * 2048 + d;
    float acc = load1(cb, cbo + d, isbf) + wv.w * b2f(base[0]);
    if (l >= 1) acc += wv.z * b2f(base[-2048]);
    if (l >= 2) acc += wv.y * b2f(base[-4096]);
    if (l >= 3) acc += wv.x * b2f(base[-6144]);
    xc[idx] = f2b(silu_(acc));
}

// ---------------- scan phase 1 (CH=16; xc now bf16) ----------------
__global__ __launch_bounds__(256) void scan_phase1(
    const float* __restrict__ dtb, const u16* __restrict__ xcb,
    const float* __restrict__ dbc, const void* __restrict__ Alog, size_t alo,
    float* __restrict__ Sdt, float* __restrict__ Sbuf,
    const float* __restrict__ flagp)
{
    const bool isbf = (*flagp > 0.5f);
    __shared__ float sB[CH][16];
    const int blk = blockIdx.x;
    const int dblk = blk & 3;
    const int c = (blk >> 2) & (NC - 1);
    const int b = blk >> 9;
    const int d = dblk * 256 + threadIdx.x;
    const int row0 = b * L_ + c * CH;
    if (threadIdx.x < CH * 4) {
        const int l = threadIdx.x >> 2, s4 = (threadIdx.x & 3) << 2;
        *(float4*)&sB[l][s4] = *(const float4*)&dbc[(size_t)(row0 + l) * 64 + 32 + s4];
    }
    __syncthreads();
    float A[DS];
    #pragma unroll
    for (int s = 0; s < DS; s++) A[s] = -expf(load1(Alog, alo + (size_t)d * DS + s, isbf));
    float h[DS];
    #pragma unroll
    for (int s = 0; s < DS; s++) h[s] = 0.f;
    float sdt = 0.f;
    for (int l = 0; l < CH; l++) {
        const int row = row0 + l;
        const float dtv = dtb[(size_t)row * DI + d];
        const float xv  = b2f(xcb[(size_t)row * DI + d]);
        sdt += dtv;
        const float dtx = dtv * xv;
        #pragma unroll
        for (int s = 0; s < DS; s++) {
            const float dA = expf(dtv * A[s]);
            h[s] = fmaf(dA, h[s], dtx * sB[l][s]);
        }
    }
    const int cb_ = b * NC + c;
    Sdt[(size_t)cb_ * DI + d] = sdt;
    #pragma unroll
    for (int s = 0; s < DS; s++) Sbuf[((size_t)cb_ * DS + s) * DI + d] = h[s];
}

// ---------------- scan phase 2 (in-place exclusive; r6 verbatim) ----------------
__global__ __launch_bounds__(256) void scan_phase2(
    const float* __restrict__ Sdt, float* __restrict__ Sbuf,
    const void* __restrict__ Alog, size_t alo,
    const float* __restrict__ flagp)
{
    const bool isbf = (*flagp > 0.5f);
    const int g = blockIdx.x * 256 + threadIdx.x;
    const int d = g & (DI - 1);
    const int s = (g >> 10) & (DS - 1);
    const int b = g >> 14;
    const float A = -expf(load1(Alog, alo + (size_t)d * DS + s, isbf));
    float h = 0.f;
    for (int c = 0; c < NC; c++) {
        const int cb_ = b * NC + c;
        const size_t idx = ((size_t)cb_ * DS + s) * DI + d;
        const float tmp = Sbuf[idx];
        Sbuf[idx] = h;
        const float P = expf(A * Sdt[(size_t)cb_ * DI + d]);
        h = fmaf(P, h, tmp);
    }
}

// ---------------- scan phase 3 (CH=16; xc/xz bf16, y written bf16 in-place) ----------------
__global__ __launch_bounds__(256) void scan_phase3(
    const float* __restrict__ dtb, u16* __restrict__ xcb,
    const float* __restrict__ dbc, const void* __restrict__ Alog, size_t alo,
    const float* __restrict__ H0, const void* __restrict__ Dpv, size_t dpo,
    const u16* __restrict__ xz, const float* __restrict__ flagp)
{
    const bool isbf = (*flagp > 0.5f);
    __shared__ float sBC[CH][32];
    const int blk = blockIdx.x;
    const int dblk = blk & 3;
    const int c = (blk >> 2) & (NC - 1);
    const int b = blk >> 9;
    const int d = dblk * 256 + threadIdx.x;
    const int row0 = b * L_ + c * CH;
    if (threadIdx.x < CH * 8) {
        const int l = threadIdx.x >> 3, q = (threadIdx.x & 7) << 2;
        *(float4*)&sBC[l][q] = *(const float4*)&dbc[(size_t)(row0 + l) * 64 + 32 + q];
    }
    __syncthreads();
    float A[DS];
    #pragma unroll
    for (int s = 0; s < DS; s++) A[s] = -expf(load1(Alog, alo + (size_t)d * DS + s, isbf));
    const int cb_ = b * NC + c;
    float h[DS];
    #pragma unroll
    for (int s = 0; s < DS; s++) h[s] = H0[((size_t)cb_ * DS + s) * DI + d];
    const float Dpd = load1(Dpv, dpo + d, isbf);
    for (int l = 0; l < CH; l++) {
        const int row = row0 + l;
        const float dtv = dtb[(size_t)row * DI + d];
        const float xv  = b2f(xcb[(size_t)row * DI + d]);
        const float dtx = dtv * xv;
        float y = 0.f;
        #pragma unroll
        for (int s = 0; s < DS; s++) {
            const float dA = expf(dtv * A[s]);
            h[s] = fmaf(dA, h[s], dtx * sBC[l][s]);
            y = fmaf(h[s], sBC[l][16 + s], y);
        }
        y = fmaf(xv, Dpd, y);
        y *= silu_(b2f(xz[(size_t)row * 2048 + DI + d]));
        xcb[(size_t)row * DI + d] = f2b(y);
    }
}

__global__ void cast_in(const void* __restrict__ in, float* __restrict__ outf,
                        u16* __restrict__ outb, int n, const float* __restrict__ flagp) {
    const bool isbf = (*flagp > 0.5f);
    const int i = blockIdx.x * 256 + threadIdx.x;
    if (i < n) {
        const float v = load1(in, (size_t)i, isbf);
        outf[i] = v;
        outb[i] = f2b(v);
    }
}
__global__ void cast_out(const float* __restrict__ in, void* __restrict__ out, int n,
                         const float* __restrict__ flagp) {
    const bool isbf = (*flagp > 0.5f);
    const int i = blockIdx.x * 256 + threadIdx.x;
    if (i < n) {
        if (isbf) ((u16*)out)[i] = f2b(in[i]);
        else      ((float*)out)[i] = in[i];
    }
}

extern "C" void kernel_launch(void* const* d_in, const int* in_sizes, int n_in,
                              void* d_out, int out_size, void* d_ws, size_t ws_size,
                              hipStream_t stream)
{
    const void* x_in  = d_in[0];
    const void* W_in  = d_in[1];
    const void* convw = d_in[2];
    const void* convb = d_in[3];
    const void* W_x   = d_in[4];
    const void* W_dt  = d_in[5];
    const void* b_dt  = d_in[6];
    const void* A_log = d_in[7];
    const void* Dp    = d_in[8];
    const void* W_out = d_in[9];

    char* base = (char*)d_ws;
    float* flag  = (float*)base;                     base += 16;
    u16*   xz    = (u16*)base;                       base += (size_t)MROWS * 2048 * 2;  // 16 MB
    u16*   xc    = (u16*)base;                       base += (size_t)MROWS * DI * 2;    // 8 MB
    u16*   xb_bf = (u16*)base;                       base += (size_t)MROWS * DM * 2;    // 4 MB
    float* dbc   = (float*)base;                     base += (size_t)MROWS * 64 * 4;    // 1 MB
    float* dtb   = (float*)base;                     base += (size_t)MROWS * DI * 4;    // 16 MB
    float* Sdt   = (float*)base;                     base += (size_t)2 * NC * DI * 4;   // 1 MB
    float* Sbuf  = (float*)base;                     base += (size_t)2 * NC * DS * DI * 4; // 16 MB
    float* xb_f  = (float*)base;                     base += (size_t)MROWS * DM * 4;    // 8 MB
    u16*   WinT  = (u16*)base;                       base += (size_t)NBLK * 2048 * DM * 2; // 8 MB
    u16*   WxT   = (u16*)base;                       base += (size_t)NBLK * 64 * DI * 2;   // 0.5 MB
    u16*   WoutT = (u16*)base;                       base += (size_t)NBLK * DM * DI * 2;   // 4 MB

    probe_dtype<<<1, 256, 0, stream>>>(x_in, flag);
    // batched weight transposes: [K][N] -> bf16 [N][K], all 4 layers
    transpose_wb<<<dim3(2048 / 32, DM / 32, NBLK), 256, 0, stream>>>(W_in, DM, 2048, WinT, flag);
    transpose_wb<<<dim3(64 / 32, DI / 32, NBLK), 256, 0, stream>>>(W_x, DI, 64, WxT, flag);
    transpose_wb<<<dim3(DM / 32, DI / 32, NBLK), 256, 0, stream>>>(W_out, DI, DM, WoutT, flag);
    cast_in<<<(MROWS * DM) / 256, 256, 0, stream>>>(x_in, xb_f, xb_bf, MROWS * DM, flag);

    for (int i = 0; i < NBLK; i++) {
        // xz = x @ W_in  (4096 x 2048, K=512) -- 128x128 tile, bf16 out
        gemm_bf<128, 4, 0><<<dim3(2048 / 128, MROWS / 128), 256, 0, stream>>>(
            xb_bf, DM, WinT + (size_t)i * 2048 * DM, DM, xz, nullptr, 2048, nullptr);
        // xc = silu(conv(xi) + cb)  (bf16 -> bf16)
        conv_silu<<<(MROWS * DI) / 256, 256, 0, stream>>>(
            xz, convw, (size_t)i * DI * 4, convb, (size_t)i * DI, xc, flag);
        // dbc = xc @ W_x  (4096 x 64, K=1024) -- fp32 out
        gemm_bf<64, 1, 1><<<dim3(1, MROWS / 32), 256, 0, stream>>>(
            xc, DI, WxT + (size_t)i * 64 * DI, DI, nullptr, dbc, 64, nullptr);
        // dt = softplus(dt_raw @ W_dt + b_dt)  (4096 x 1024, K=32) -- fp32 VALU
        gemm_f32<1><<<dim3(DI / 64, MROWS / 64), 256, 0, stream>>>(
            dbc, 64, W_dt, (size_t)i * 32 * DI, DI, dtb, DI, 32, b_dt, (size_t)i * DI, nullptr, flag);
        // selective scan: 128 chunks x 16 steps
        scan_phase1<<<2 * NC * 4, 256, 0, stream>>>(dtb, xc, dbc, A_log, (size_t)i * DI * DS,
                                                    Sdt, Sbuf, flag);
        scan_phase2<<<128, 256, 0, stream>>>(Sdt, Sbuf, A_log, (size_t)i * DI * DS, flag);
        scan_phase3<<<2 * NC * 4, 256, 0, stream>>>(dtb, xc, dbc, A_log, (size_t)i * DI * DS,
                                                    Sbuf, Dp, (size_t)i * DI, xz, flag);
        // out = y @ W_out + resid  (4096 x 512, K=1024) -- dual-store fp32 + bf16
        gemm_bf<64, 2, 2><<<dim3(DM / 64, MROWS / 64), 256, 0, stream>>>(
            xc, DI, WoutT + (size_t)i * DM * DI, DI, xb_bf, xb_f, DM, xb_f);
    }
    cast_out<<<(MROWS * DM) / 256, 256, 0, stream>>>(xb_f, d_out, MROWS * DM, flag);
}

// Round 9
// 667.111 us; speedup vs baseline: 2.7209x; 1.4884x over previous
//
#include <hip/hip_runtime.h>

// MambaEncoder: B=2, L=2048, D_MODEL=512, D_INNER=1024, DT_RANK=32, D_STATE=16, 4 blocks.
// Round 9 (from r8 @993us; GEMM still latency-stalled, 2.8x write amp):
// (1) gemm_lds: m97 structure -- global_load_lds(16B) DMA staging, unpadded [row][32] LDS
//     (64B-stride fragment reads are throughput-conflict-free), 2-barrier K-loop, plus
//     LDS-transposed epilogue for full-line coalesced bf16/fp32 stores.
// (2) dt-GEMM fused into scan p1/p3 (W_dt[:,d] in 32 VGPRs, softplus inline) -- dtb deleted.
// (3) NC=64 (halves Sbuf traffic); __expf/__logf in scans+conv.

#define L_    2048
#define DM    512
#define DI    1024
#define DS    16
#define NBLK  4
#define NC    64
#define CH    32
#define MROWS 4096   // B_ * L_

using u16 = unsigned short;
typedef __bf16 bf16x8 __attribute__((ext_vector_type(8)));
typedef float  f32x4  __attribute__((ext_vector_type(4)));

__device__ __forceinline__ float b2f(u16 u) {
    union { unsigned int i; float f; } v; v.i = ((unsigned int)u) << 16; return v.f;
}
__device__ __forceinline__ u16 f2b(float f) {
    union { float f; unsigned int i; } v; v.f = f;
    unsigned int x = v.i;
    return (u16)((x + 0x7FFFu + ((x >> 16) & 1u)) >> 16);
}
__device__ __forceinline__ float silu_(float x) { return x / (1.f + __expf(-x)); }

struct F4 { float x, y, z, w; };
__device__ __forceinline__ F4 load4(const void* p, size_t e, bool isbf) {
    F4 r;
    if (isbf) {
        ushort4 v = *(const ushort4*)((const u16*)p + e);
        r.x = b2f(v.x); r.y = b2f(v.y); r.z = b2f(v.z); r.w = b2f(v.w);
    } else {
        float4 v = *(const float4*)((const float*)p + e);
        r.x = v.x; r.y = v.y; r.z = v.z; r.w = v.w;
    }
    return r;
}
__device__ __forceinline__ float load1(const void* p, size_t e, bool isbf) {
    return isbf ? b2f(((const u16*)p)[e]) : ((const float*)p)[e];
}

// async 16B global -> LDS (wave-uniform LDS base + lane*16)
__device__ __forceinline__ void async16(const u16* g, u16* l) {
    __builtin_amdgcn_global_load_lds(
        (const __attribute__((address_space(1))) unsigned int*)g,
        (__attribute__((address_space(3))) unsigned int*)l, 16, 0, 0);
}

// ---------------- dtype probe ----------------
__global__ void probe_dtype(const void* x, float* flag) {
    __shared__ int allok;
    if (threadIdx.x == 0) allok = 1;
    __syncthreads();
    const u16* p = (const u16*)x;
    bool ok = true;
    for (int i = threadIdx.x; i < 2048; i += 256) {
        float v = b2f(p[i]);
        if (!(v == v) || fabsf(v) >= 1000.f) ok = false;
    }
    if (!ok) allok = 0;
    __syncthreads();
    if (threadIdx.x == 0) flag[0] = allok ? 1.f : 0.f;
}

// ---------------- weight transpose: src[z][R][C] (flag dtype) -> dst[z][C][R] bf16 ----------------
__global__ __launch_bounds__(256) void transpose_wb(
    const void* __restrict__ src, int R, int C,
    u16* __restrict__ dst, const float* __restrict__ flagp)
{
    const bool isbf = (*flagp > 0.5f);
    __shared__ u16 t[32][33];
    const size_t mo = (size_t)blockIdx.z * R * C;
    const int c0 = blockIdx.x * 32, r0 = blockIdx.y * 32;
    const int tx = threadIdx.x & 31, ty = threadIdx.x >> 5;
    #pragma unroll
    for (int i = 0; i < 32; i += 8)
        t[ty + i][tx] = f2b(load1(src, mo + (size_t)(r0 + ty + i) * C + c0 + tx, isbf));
    __syncthreads();
    #pragma unroll
    for (int i = 0; i < 32; i += 8)
        dst[mo + (size_t)(c0 + ty + i) * R + r0 + tx] = t[tx][ty + i];
}

// ---------------- gemm_lds: C = A(bf16,[M][K]) @ BT(bf16,[N][K])^T  (m97 structure) ----------------
// BM=32*MT, BK=32, 256 threads = 4 waves (2x2). global_load_lds 16B staging into unpadded
// [row][32] LDS; 2-barrier K-loop; LDS-transposed epilogue for coalesced stores.
// OM 0: bf16 Cb. OM 2: +resid (coalesced), dual-store bf16 Cb + fp32 Cf (in-place safe).
template<int BN, int MT, int OM>
__global__ __launch_bounds__(256) void gemm_lds(
    const u16* __restrict__ A, int lda,
    const u16* __restrict__ BT, int Kd,
    u16* __restrict__ Cb, float* __restrict__ Cf, int ldc,
    const float* __restrict__ resid)
{
    constexpr int BM = 32 * MT;
    constexpr int NT = BN / 32;
    constexpr int W  = NT * 16;            // per-wave n width
    constexpr int CA = BM * 4;             // A chunks (16B each)
    constexpr int T  = CA + BN * 4;        // total chunks
    constexpr int PW = T / 4;              // chunks per wave
    constexpr int NI = PW / 64;            // insts per wave
    constexpr int STG = (BM + BN) * 32;    // staging size (u16)
    constexpr int EPI = 4 * 16 * (W + 4) * 2;  // epilogue f32 region (u16 units)
    constexpr int LN  = STG > EPI ? STG : EPI;
    __shared__ u16 sL[LN];
    u16* sA = sL;
    u16* sB = sL + BM * 32;
    const int tid = threadIdx.x;
    const int lane = tid & 63;
    const int wid = tid >> 6;
    const int wm = wid >> 1, wn = wid & 1;
    const int m0 = blockIdx.y * BM;
    const int n0 = blockIdx.x * BN;
    const int col16 = lane & 15, quad = lane >> 4;

    f32x4 acc[MT][NT];
    #pragma unroll
    for (int i = 0; i < MT; i++)
        #pragma unroll
        for (int j = 0; j < NT; j++) acc[i][j] = {0.f, 0.f, 0.f, 0.f};

    for (int k0 = 0; k0 < Kd; k0 += 32) {
        #pragma unroll
        for (int it = 0; it < NI; it++) {
            const int cbase = wid * PW + it * 64;
            const int c = cbase + lane;
            const u16* g;
            if (cbase < CA)
                g = A + (size_t)(m0 + (c >> 2)) * lda + k0 + ((c & 3) << 3);
            else {
                const int cc = c - CA;
                g = BT + (size_t)(n0 + (cc >> 2)) * Kd + k0 + ((cc & 3) << 3);
            }
            async16(g, sL + (size_t)cbase * 8);
        }
        __syncthreads();                    // drains vmcnt -> LDS populated
        bf16x8 af[MT], bfr[NT];
        #pragma unroll
        for (int mi = 0; mi < MT; mi++)
            af[mi] = *(const bf16x8*)&sA[(wm * 16 * MT + mi * 16 + col16) * 32 + quad * 8];
        #pragma unroll
        for (int ni = 0; ni < NT; ni++)
            bfr[ni] = *(const bf16x8*)&sB[(wn * (BN / 2) + ni * 16 + col16) * 32 + quad * 8];
        #pragma unroll
        for (int mi = 0; mi < MT; mi++)
            #pragma unroll
            for (int ni = 0; ni < NT; ni++)
                acc[mi][ni] = __builtin_amdgcn_mfma_f32_16x16x32_bf16(
                    af[mi], bfr[ni], acc[mi][ni], 0, 0, 0);
        __syncthreads();                    // LDS free for next tile
    }

    // epilogue: stage per-wave [16][W] f32 in LDS, store full-row coalesced
    __syncthreads();                        // all waves done reading staging LDS
    float* sw = (float*)sL + wid * 16 * (W + 4);
    constexpr int LPR = W / 8;              // lanes per row (8 bf16 per lane)
    constexpr int RPP = 64 / LPR;           // rows per pass
    constexpr int NP  = 16 / RPP;           // passes
    #pragma unroll
    for (int mi = 0; mi < MT; mi++) {
        #pragma unroll
        for (int ni = 0; ni < NT; ni++)
            #pragma unroll
            for (int rr = 0; rr < 4; rr++)
                sw[(quad * 4 + rr) * (W + 4) + ni * 16 + col16] = acc[mi][ni][rr];
        #pragma unroll
        for (int p = 0; p < NP; p++) {
            const int row = p * RPP + lane / LPR;
            const int colg = (lane % LPR) * 8;
            float4 v0 = *(const float4*)&sw[row * (W + 4) + colg];
            float4 v1 = *(const float4*)&sw[row * (W + 4) + colg + 4];
            const int grow = m0 + wm * 16 * MT + mi * 16 + row;
            const int gcol = n0 + wn * (BN / 2) + colg;
            if (OM == 2) {
                const float4 r0 = *(const float4*)&resid[(size_t)grow * ldc + gcol];
                const float4 r1 = *(const float4*)&resid[(size_t)grow * ldc + gcol + 4];
                v0.x += r0.x; v0.y += r0.y; v0.z += r0.z; v0.w += r0.w;
                v1.x += r1.x; v1.y += r1.y; v1.z += r1.z; v1.w += r1.w;
                *(float4*)&Cf[(size_t)grow * ldc + gcol]     = v0;
                *(float4*)&Cf[(size_t)grow * ldc + gcol + 4] = v1;
            }
            ushort4 b0 = make_ushort4(f2b(v0.x), f2b(v0.y), f2b(v0.z), f2b(v0.w));
            ushort4 b1 = make_ushort4(f2b(v1.x), f2b(v1.y), f2b(v1.z), f2b(v1.w));
            *(ushort4*)&Cb[(size_t)grow * ldc + gcol]     = b0;
            *(ushort4*)&Cb[(size_t)grow * ldc + gcol + 4] = b1;
        }
    }
}

// ---------------- gemm_bf (register-prefetch; GEMM2 only, fp32 out) ----------------
template<int BN, int MT>
__global__ __launch_bounds__(256) void gemm_bf(
    const u16* __restrict__ A, int lda,
    const u16* __restrict__ BT, int Kd,
    float* __restrict__ Cf, int ldc)
{
    constexpr int NT = BN / 32;
    constexpr int BM = 32 * MT;
    constexpr int ASL = BM * 4;
    constexpr int AIT = (ASL + 255) / 256;
    constexpr int BSL = BN * 4;
    constexpr int BIT = (BSL + 255) / 256;
    __shared__ u16 sA[BM][40];
    __shared__ u16 sB[BN][40];
    const int tid = threadIdx.x;
    const int lane = tid & 63;
    const int wid = tid >> 6;
    const int wm = wid >> 1, wn = wid & 1;
    const int m0 = blockIdx.y * BM;
    const int n0 = blockIdx.x * BN;
    const int col16 = lane & 15, quad = lane >> 4;

    f32x4 acc[MT][NT];
    #pragma unroll
    for (int i = 0; i < MT; i++)
        #pragma unroll
        for (int j = 0; j < NT; j++) acc[i][j] = {0.f, 0.f, 0.f, 0.f};

    int4 fa[AIT], fb[BIT];
    #pragma unroll
    for (int it = 0; it < AIT; it++) {
        const int slot = tid + it * 256;
        if (slot < ASL)
            fa[it] = *(const int4*)&A[(size_t)(m0 + (slot >> 2)) * lda + ((slot & 3) << 3)];
    }
    #pragma unroll
    for (int it = 0; it < BIT; it++) {
        const int slot = tid + it * 256;
        if (slot < BSL)
            fb[it] = *(const int4*)&BT[(size_t)(n0 + (slot >> 2)) * Kd + ((slot & 3) << 3)];
    }

    for (int k0 = 0;;) {
        __syncthreads();
        #pragma unroll
        for (int it = 0; it < AIT; it++) {
            const int slot = tid + it * 256;
            if (slot < ASL) *(int4*)&sA[slot >> 2][(slot & 3) << 3] = fa[it];
        }
        #pragma unroll
        for (int it = 0; it < BIT; it++) {
            const int slot = tid + it * 256;
            if (slot < BSL) *(int4*)&sB[slot >> 2][(slot & 3) << 3] = fb[it];
        }
        __syncthreads();
        k0 += 32;
        const bool more = (k0 < Kd);
        if (more) {
            #pragma unroll
            for (int it = 0; it < AIT; it++) {
                const int slot = tid + it * 256;
                if (slot < ASL)
                    fa[it] = *(const int4*)&A[(size_t)(m0 + (slot >> 2)) * lda + k0 + ((slot & 3) << 3)];
            }
            #pragma unroll
            for (int it = 0; it < BIT; it++) {
                const int slot = tid + it * 256;
                if (slot < BSL)
                    fb[it] = *(const int4*)&BT[(size_t)(n0 + (slot >> 2)) * Kd + k0 + ((slot & 3) << 3)];
            }
        }
        bf16x8 af[MT], bfr[NT];
        #pragma unroll
        for (int mi = 0; mi < MT; mi++)
            af[mi] = *(const bf16x8*)&sA[wm * (16 * MT) + mi * 16 + col16][quad * 8];
        #pragma unroll
        for (int ni = 0; ni < NT; ni++)
            bfr[ni] = *(const bf16x8*)&sB[wn * (BN / 2) + ni * 16 + col16][quad * 8];
        #pragma unroll
        for (int mi = 0; mi < MT; mi++)
            #pragma unroll
            for (int ni = 0; ni < NT; ni++)
                acc[mi][ni] = __builtin_amdgcn_mfma_f32_16x16x32_bf16(
                    af[mi], bfr[ni], acc[mi][ni], 0, 0, 0);
        if (!more) break;
    }
    #pragma unroll
    for (int mi = 0; mi < MT; mi++)
        #pragma unroll
        for (int ni = 0; ni < NT; ni++)
            #pragma unroll
            for (int rr = 0; rr < 4; rr++) {
                const int row = m0 + wm * (16 * MT) + mi * 16 + quad * 4 + rr;
                const int col = n0 + wn * (BN / 2) + ni * 16 + col16;
                Cf[(size_t)row * ldc + col] = acc[mi][ni][rr];
            }
}

// ---------------- depthwise causal conv(4) + bias + SiLU (bf16 in/out) ----------------
__global__ __launch_bounds__(256) void conv_silu(
    const u16* __restrict__ xz, const void* __restrict__ cw, size_t cwo,
    const void* __restrict__ cb, size_t cbo, u16* __restrict__ xc,
    const float* __restrict__ flagp)
{
    const bool isbf = (*flagp > 0.5f);
    const int idx = blockIdx.x * 256 + threadIdx.x;
    const int d = idx & (DI - 1);
    const int row = idx >> 10;
    const int l = row & (L_ - 1);
    const F4 wv = load4(cw, cwo + (size_t)d * 4, isbf);
    const u16* base = xz + (size_t)row * 2048 + d;
    float acc = load1(cb, cbo + d, isbf) + wv.w * b2f(base[0]);
    if (l >= 1) acc += wv.z * b2f(base[-2048]);
    if (l >= 2) acc += wv.y * b2f(base[-4096]);
    if (l >= 3) acc += wv.x * b2f(base[-6144]);
    xc[idx] = f2b(silu_(acc));
}

// ---------------- scan phase 1 (fused dt; CH=32, NC=64) ----------------
__global__ __launch_bounds__(256) void scan_phase1(
    const u16* __restrict__ xcb, const float* __restrict__ dbc,
    const void* __restrict__ Wdt, size_t wdto,
    const void* __restrict__ bdt, size_t bdto,
    const void* __restrict__ Alog, size_t alo,
    float* __restrict__ Sdt, float* __restrict__ Sbuf,
    const float* __restrict__ flagp)
{
    const bool isbf = (*flagp > 0.5f);
    __shared__ float sD[CH][64];
    const int blk = blockIdx.x;               // 2*64*4 = 512
    const int dblk = blk & 3;
    const int c = (blk >> 2) & (NC - 1);
    const int b = blk >> 8;
    const int d = dblk * 256 + threadIdx.x;
    const int row0 = b * L_ + c * CH;
    #pragma unroll
    for (int t = threadIdx.x; t < CH * 16; t += 256) {
        const int r = t >> 4, c4 = (t & 15) << 2;
        *(float4*)&sD[r][c4] = *(const float4*)&dbc[(size_t)(row0 + r) * 64 + c4];
    }
    __syncthreads();
    float wdt[32];
    #pragma unroll
    for (int r = 0; r < 32; r++) wdt[r] = load1(Wdt, wdto + (size_t)r * DI + d, isbf);
    const float bdtv = load1(bdt, bdto + d, isbf);
    float A[DS], h[DS];
    #pragma unroll
    for (int s = 0; s < DS; s++) { A[s] = -__expf(load1(Alog, alo + (size_t)d * DS + s, isbf)); h[s] = 0.f; }
    float sdt = 0.f;
    for (int l = 0; l < CH; l++) {
        float dtr = bdtv;
        #pragma unroll
        for (int r = 0; r < 32; r++) dtr = fmaf(sD[l][r], wdt[r], dtr);
        const float dt = (dtr > 20.f) ? dtr : __logf(1.f + __expf(dtr));
        const float xv = b2f(xcb[(size_t)(row0 + l) * DI + d]);
        sdt += dt;
        const float dtx = dt * xv;
        #pragma unroll
        for (int s = 0; s < DS; s++)
            h[s] = fmaf(__expf(dt * A[s]), h[s], dtx * sD[l][32 + s]);
    }
    const int cb_ = b * NC + c;
    Sdt[(size_t)cb_ * DI + d] = sdt;
    #pragma unroll
    for (int s = 0; s < DS; s++) Sbuf[((size_t)cb_ * DS + s) * DI + d] = h[s];
}

// ---------------- scan phase 2: in-place exclusive scan (NC=64) ----------------
__global__ __launch_bounds__(256) void scan_phase2(
    const float* __restrict__ Sdt, float* __restrict__ Sbuf,
    const void* __restrict__ Alog, size_t alo,
    const float* __restrict__ flagp)
{
    const bool isbf = (*flagp > 0.5f);
    const int g = blockIdx.x * 256 + threadIdx.x;
    const int d = g & (DI - 1);
    const int s = (g >> 10) & (DS - 1);
    const int b = g >> 14;
    const float A = -__expf(load1(Alog, alo + (size_t)d * DS + s, isbf));
    float h = 0.f;
    for (int c = 0; c < NC; c++) {
        const int cb_ = b * NC + c;
        const size_t idx = ((size_t)cb_ * DS + s) * DI + d;
        const float tmp = Sbuf[idx];
        Sbuf[idx] = h;
        const float P = __expf(A * Sdt[(size_t)cb_ * DI + d]);
        h = fmaf(P, h, tmp);
    }
}

// ---------------- scan phase 3 (fused dt; y/D/z-gate; CH=32) ----------------
__global__ __launch_bounds__(256) void scan_phase3(
    u16* __restrict__ xcb, const float* __restrict__ dbc,
    const void* __restrict__ Wdt, size_t wdto,
    const void* __restrict__ bdt, size_t bdto,
    const void* __restrict__ Alog, size_t alo,
    const float* __restrict__ H0, const void* __restrict__ Dpv, size_t dpo,
    const u16* __restrict__ xz, const float* __restrict__ flagp)
{
    const bool isbf = (*flagp > 0.5f);
    __shared__ float sD[CH][64];
    const int blk = blockIdx.x;
    const int dblk = blk & 3;
    const int c = (blk >> 2) & (NC - 1);
    const int b = blk >> 8;
    const int d = dblk * 256 + threadIdx.x;
    const int row0 = b * L_ + c * CH;
    #pragma unroll
    for (int t = threadIdx.x; t < CH * 16; t += 256) {
        const int r = t >> 4, c4 = (t & 15) << 2;
        *(float4*)&sD[r][c4] = *(const float4*)&dbc[(size_t)(row0 + r) * 64 + c4];
    }
    __syncthreads();
    float wdt[32];
    #pragma unroll
    for (int r = 0; r < 32; r++) wdt[r] = load1(Wdt, wdto + (size_t)r * DI + d, isbf);
    const float bdtv = load1(bdt, bdto + d, isbf);
    float A[DS], h[DS];
    const int cb_ = b * NC + c;
    #pragma unroll
    for (int s = 0; s < DS; s++) {
        A[s] = -__expf(load1(Alog, alo + (size_t)d * DS + s, isbf));
        h[s] = H0[((size_t)cb_ * DS + s) * DI + d];
    }
    const float Dpd = load1(Dpv, dpo + d, isbf);
    for (int l = 0; l < CH; l++) {
        float dtr = bdtv;
        #pragma unroll
        for (int r = 0; r < 32; r++) dtr = fmaf(sD[l][r], wdt[r], dtr);
        const float dt = (dtr > 20.f) ? dtr : __logf(1.f + __expf(dtr));
        const int row = row0 + l;
        const float xv = b2f(xcb[(size_t)row * DI + d]);
        const float dtx = dt * xv;
        float y = 0.f;
        #pragma unroll
        for (int s = 0; s < DS; s++) {
            h[s] = fmaf(__expf(dt * A[s]), h[s], dtx * sD[l][32 + s]);
            y = fmaf(h[s], sD[l][48 + s], y);
        }
        y = fmaf(xv, Dpd, y);
        y *= silu_(b2f(xz[(size_t)row * 2048 + DI + d]));
        xcb[(size_t)row * DI + d] = f2b(y);
    }
}

__global__ void cast_in(const void* __restrict__ in, float* __restrict__ outf,
                        u16* __restrict__ outb, int n, const float* __restrict__ flagp) {
    const bool isbf = (*flagp > 0.5f);
    const int i = blockIdx.x * 256 + threadIdx.x;
    if (i < n) {
        const float v = load1(in, (size_t)i, isbf);
        outf[i] = v;
        outb[i] = f2b(v);
    }
}
__global__ void cast_out(const float* __restrict__ in, void* __restrict__ out, int n,
                         const float* __restrict__ flagp) {
    const bool isbf = (*flagp > 0.5f);
    const int i = blockIdx.x * 256 + threadIdx.x;
    if (i < n) {
        if (isbf) ((u16*)out)[i] = f2b(in[i]);
        else      ((float*)out)[i] = in[i];
    }
}

extern "C" void kernel_launch(void* const* d_in, const int* in_sizes, int n_in,
                              void* d_out, int out_size, void* d_ws, size_t ws_size,
                              hipStream_t stream)
{
    const void* x_in  = d_in[0];
    const void* W_in  = d_in[1];
    const void* convw = d_in[2];
    const void* convb = d_in[3];
    const void* W_x   = d_in[4];
    const void* W_dt  = d_in[5];
    const void* b_dt  = d_in[6];
    const void* A_log = d_in[7];
    const void* Dp    = d_in[8];
    const void* W_out = d_in[9];

    char* base = (char*)d_ws;
    float* flag  = (float*)base;                     base += 16;
    u16*   xz    = (u16*)base;                       base += (size_t)MROWS * 2048 * 2;   // 16 MB
    u16*   xc    = (u16*)base;                       base += (size_t)MROWS * DI * 2;     // 8 MB
    u16*   xb_bf = (u16*)base;                       base += (size_t)MROWS * DM * 2;     // 4 MB
    float* dbc   = (float*)base;                     base += (size_t)MROWS * 64 * 4;     // 1 MB
    float* Sdt   = (float*)base;                     base += (size_t)2 * NC * DI * 4;    // 0.5 MB
    float* Sbuf  = (float*)base;                     base += (size_t)2 * NC * DS * DI * 4; // 8 MB
    float* xb_f  = (float*)base;                     base += (size_t)MROWS * DM * 4;     // 8 MB
    u16*   WinT  = (u16*)base;                       base += (size_t)NBLK * 2048 * DM * 2;  // 8 MB
    u16*   WxT   = (u16*)base;                       base += (size_t)NBLK * 64 * DI * 2;    // 0.5 MB
    u16*   WoutT = (u16*)base;                       base += (size_t)NBLK * DM * DI * 2;    // 4 MB

    probe_dtype<<<1, 256, 0, stream>>>(x_in, flag);
    transpose_wb<<<dim3(2048 / 32, DM / 32, NBLK), 256, 0, stream>>>(W_in, DM, 2048, WinT, flag);
    transpose_wb<<<dim3(64 / 32, DI / 32, NBLK), 256, 0, stream>>>(W_x, DI, 64, WxT, flag);
    transpose_wb<<<dim3(DM / 32, DI / 32, NBLK), 256, 0, stream>>>(W_out, DI, DM, WoutT, flag);
    cast_in<<<(MROWS * DM) / 256, 256, 0, stream>>>(x_in, xb_f, xb_bf, MROWS * DM, flag);

    for (int i = 0; i < NBLK; i++) {
        // xz = x @ W_in  (4096 x 2048, K=512) -- gemm_lds 128x128
        gemm_lds<128, 4, 0><<<dim3(2048 / 128, MROWS / 128), 256, 0, stream>>>(
            xb_bf, DM, WinT + (size_t)i * 2048 * DM, DM, xz, nullptr, 2048, nullptr);
        // xc = silu(conv(xi) + cb)
        conv_silu<<<(MROWS * DI) / 256, 256, 0, stream>>>(
            xz, convw, (size_t)i * DI * 4, convb, (size_t)i * DI, xc, flag);
        // dbc = xc @ W_x  (4096 x 64, K=1024) -- register-pipeline, fp32 out
        gemm_bf<64, 1><<<dim3(1, MROWS / 32), 256, 0, stream>>>(
            xc, DI, WxT + (size_t)i * 64 * DI, DI, dbc, 64);
        // selective scan (dt fused): 64 chunks x 32 steps
        scan_phase1<<<2 * NC * 4, 256, 0, stream>>>(
            xc, dbc, W_dt, (size_t)i * 32 * DI, b_dt, (size_t)i * DI,
            A_log, (size_t)i * DI * DS, Sdt, Sbuf, flag);
        scan_phase2<<<128, 256, 0, stream>>>(Sdt, Sbuf, A_log, (size_t)i * DI * DS, flag);
        scan_phase3<<<2 * NC * 4, 256, 0, stream>>>(
            xc, dbc, W_dt, (size_t)i * 32 * DI, b_dt, (size_t)i * DI,
            A_log, (size_t)i * DI * DS, Sbuf, Dp, (size_t)i * DI, xz, flag);
        // out = y @ W_out + resid  (4096 x 512, K=1024) -- gemm_lds 64x64, dual-store
        gemm_lds<64, 2, 2><<<dim3(DM / 64, MROWS / 64), 256, 0, stream>>>(
            xc, DI, WoutT + (size_t)i * DM * DI, DI, xb_bf, xb_f, DM, xb_f);
    }
    cast_out<<<(MROWS * DM) / 256, 256, 0, stream>>>(xb_f, d_out, MROWS * DM, flag);
}